// Round 7
// baseline (280.678 us; speedup 1.0000x reference)
//
#include <hip/hip_runtime.h>
#include <hip/hip_bf16.h>
#include <math.h>

#define C_DIM 512
#define N_DIM 2048
#define B_DIM 4
#define NGRP 32
#define GCH 16          // channels per group
#define NHEAD 8
#define HDIM 64
#define EPSV 1e-6f

using f32x4  = __attribute__((ext_vector_type(4))) float;
using bf16x8 = __attribute__((ext_vector_type(8))) short;   // 8 bf16 raw bits (4 VGPRs)

// async global->LDS, 16B per lane; LDS dest = wave-uniform base + lane*16
#define GLL16(gp, lp) __builtin_amdgcn_global_load_lds( \
    (const __attribute__((address_space(1))) unsigned int*)(gp), \
    (__attribute__((address_space(3))) unsigned int*)(lp), 16, 0, 0)

static __device__ __forceinline__ unsigned short f2bf(float f) {
    union { __hip_bfloat16 h; unsigned short u; } cv;
    cv.h = __float2bfloat16(f);
    return cv.u;
}

// ---------------------------------------------------------------------------
// gn_stats: one block per (b,group); group slab contiguous (bg*32768 floats).
// ---------------------------------------------------------------------------
__global__ __launch_bounds__(256) void gn_stats(const float* __restrict__ x,
                                                float* __restrict__ stats) {
    const int GSZ = GCH * N_DIM;            // 32768
    int bg = blockIdx.x;
    const float4* x4 = (const float4*)(x + (size_t)bg * GSZ);
    int tid = threadIdx.x;

    float s = 0.f, ss = 0.f;
    #pragma unroll
    for (int it = 0; it < GSZ / 4 / 256; ++it) {
        float4 v = x4[tid + it * 256];
        s  += v.x + v.y + v.z + v.w;
        ss += v.x * v.x + v.y * v.y + v.z * v.z + v.w * v.w;
    }
    __shared__ float rs[256], rss[256];
    rs[tid] = s; rss[tid] = ss;
    __syncthreads();
    for (int off = 128; off > 0; off >>= 1) {
        if (tid < off) { rs[tid] += rs[tid + off]; rss[tid] += rss[tid + off]; }
        __syncthreads();
    }
    if (tid == 0) {
        float mean = rs[0] * (1.f / GSZ);
        float var  = rss[0] * (1.f / GSZ) - mean * mean;
        stats[bg * 2]     = mean;
        stats[bg * 2 + 1] = rsqrtf(var + EPSV);
    }
}

// ---------------------------------------------------------------------------
// gn_apply_t: x [b][c][n] fp32 -> ht [(b*n)][c] bf16 (normalized, transposed).
// ---------------------------------------------------------------------------
__global__ __launch_bounds__(256) void gn_apply_t(const float* __restrict__ x,
                                                  const float* __restrict__ stats,
                                                  const float* __restrict__ gamma,
                                                  const float* __restrict__ beta,
                                                  unsigned short* __restrict__ ht) {
    __shared__ char smem[8192];     // [64 n][64 c] bf16, rows 128B, XOR-swizzled
    int n0 = blockIdx.x * 64, c0 = blockIdx.y * 64, b = blockIdx.z;
    int tid = threadIdx.x;
    #pragma unroll
    for (int it = 0; it < 4; ++it) {
        int idx = tid + it * 256;
        int ci = idx >> 4, n4 = (idx & 15) << 2;
        int cg = c0 + ci, grp = cg >> 4;
        float mean = stats[(b * NGRP + grp) * 2];
        float rstd = stats[(b * NGRP + grp) * 2 + 1];
        float ga = gamma[cg] * rstd, be = beta[cg] - mean * ga;
        float4 v = *(const float4*)&x[((size_t)b * C_DIM + cg) * N_DIM + n0 + n4];
        float vals[4] = {v.x, v.y, v.z, v.w};
        #pragma unroll
        for (int j = 0; j < 4; ++j) {
            int nl = n4 + j;
            *(unsigned short*)(smem + nl * 128 + ((ci * 2) ^ ((nl & 7) << 4))) =
                f2bf(vals[j] * ga + be);
        }
    }
    __syncthreads();
    #pragma unroll
    for (int i = 0; i < 2; ++i) {
        int idx = tid + i * 256;       // 512 chunks = 64 rows x 8x16B
        int row = idx >> 3, ch = idx & 7;
        bf16x8 v = *(const bf16x8*)(smem + row * 128 + ((ch * 16) ^ ((row & 7) << 4)));
        *(bf16x8*)&ht[((size_t)(b * N_DIM + n0 + row)) * C_DIM + c0 + ch * 8] = v;
    }
}

// ---------------------------------------------------------------------------
// cast4: fp32 -> bf16 for the four 512x512 weights in one launch.
// dsts are contiguous (4 x 262144 shorts). grid (128, 4).
// ---------------------------------------------------------------------------
__global__ __launch_bounds__(256) void cast4_bf16(const float* __restrict__ s0,
                                                  const float* __restrict__ s1,
                                                  const float* __restrict__ s2,
                                                  const float* __restrict__ s3,
                                                  unsigned short* __restrict__ dst) {
    int which = blockIdx.y;
    const float* src = (which == 0) ? s0 : (which == 1) ? s1 : (which == 2) ? s2 : s3;
    size_t idx = (size_t)blockIdx.x * 256 + threadIdx.x;
    const float4* s4 = (const float4*)src;
    float4 a = s4[idx * 2], b = s4[idx * 2 + 1];
    bf16x8 o;
    o[0] = (short)f2bf(a.x); o[1] = (short)f2bf(a.y);
    o[2] = (short)f2bf(a.z); o[3] = (short)f2bf(a.w);
    o[4] = (short)f2bf(b.x); o[5] = (short)f2bf(b.y);
    o[6] = (short)f2bf(b.z); o[7] = (short)f2bf(b.w);
    *(bf16x8*)&dst[(size_t)which * 262144 + idx * 8] = o;
}

// ---------------------------------------------------------------------------
// conv_mfma: D[o][bn] = sum_c W[o][c] * ht[bn][c]  (+bias, modes below)
// Tile BM=64(o) x BN=128(bn) x BK=64. 4 waves, each 32x64.
// MODE 0: out bf16 natural [b][c][n]         (V conv)
// MODE 1: out bf16 [bh][n][d], *escale       (Q/K convs; one head per block)
// MODE 2: out fp32 [b][c][n] + res           (proj conv)
// ---------------------------------------------------------------------------
template <int MODE>
__global__ __launch_bounds__(256) void conv_mfma(const unsigned short* __restrict__ Wb,
                                                 const float* __restrict__ bias,
                                                 const unsigned short* __restrict__ Bsrc,
                                                 const float* __restrict__ res,
                                                 void* __restrict__ outp,
                                                 float escale) {
    __shared__ char smem[24576];
    unsigned short* As = (unsigned short*)smem;           // [64 o][64 k] swz, 8KB
    unsigned short* Bs = (unsigned short*)(smem + 8192);  // [128 n][64 k] swz, 16KB

    int bn0 = blockIdx.x * 128;      // flattened b*N + n
    int bo  = blockIdx.y * 64;
    int tid = threadIdx.x;
    int L = tid & 63, w = tid >> 6;
    int g = L >> 4, c = L & 15;
    int wr = w >> 1, wc = w & 1;

    f32x4 acc[2][4];
    #pragma unroll
    for (int t = 0; t < 2; ++t)
        #pragma unroll
        for (int u = 0; u < 4; ++u) acc[t][u] = f32x4{0.f, 0.f, 0.f, 0.f};

    for (int k0 = 0; k0 < C_DIM; k0 += 64) {
        #pragma unroll
        for (int i = 0; i < 2; ++i) {
            int j = w * 2 + i;
            int ra = j * 8 + (L >> 3);
            int sl = (L & 7) ^ (ra & 7);
            GLL16(Wb + (size_t)(bo + ra) * C_DIM + k0 + sl * 8, (char*)As + j * 1024);
        }
        #pragma unroll
        for (int i = 0; i < 4; ++i) {
            int j = w * 4 + i;
            int rb = j * 8 + (L >> 3);
            int sl = (L & 7) ^ (rb & 7);
            GLL16(Bsrc + (size_t)(bn0 + rb) * C_DIM + k0 + sl * 8, (char*)Bs + j * 1024);
        }
        __syncthreads();

        bf16x8 af[2][2], bfr[4][2];
        #pragma unroll
        for (int t = 0; t < 2; ++t) {
            int row = wr * 32 + t * 16 + c;
            #pragma unroll
            for (int ks = 0; ks < 2; ++ks)
                af[t][ks] = *(const bf16x8*)((char*)As + row * 128 +
                                             ((g * 16 + ks * 64) ^ ((row & 7) << 4)));
        }
        #pragma unroll
        for (int u = 0; u < 4; ++u) {
            int row = wc * 64 + u * 16 + c;
            #pragma unroll
            for (int ks = 0; ks < 2; ++ks)
                bfr[u][ks] = *(const bf16x8*)((char*)Bs + row * 128 +
                                              ((g * 16 + ks * 64) ^ ((row & 7) << 4)));
        }
        #pragma unroll
        for (int ks = 0; ks < 2; ++ks)
            #pragma unroll
            for (int t = 0; t < 2; ++t)
                #pragma unroll
                for (int u = 0; u < 4; ++u)
                    acc[t][u] = __builtin_amdgcn_mfma_f32_16x16x32_bf16(
                        af[t][ks], bfr[u][ks], acc[t][u], 0, 0, 0);
        __syncthreads();
    }

    int b  = bn0 >> 11;              // N_DIM = 2048
    int nb = bn0 & (N_DIM - 1);

    if (MODE == 0) {
        unsigned short* vt = (unsigned short*)outp;
        #pragma unroll
        for (int t = 0; t < 2; ++t)
            #pragma unroll
            for (int r = 0; r < 4; ++r) {
                int m = bo + wr * 32 + t * 16 + g * 4 + r;
                float bi = bias[m];
                #pragma unroll
                for (int u = 0; u < 4; ++u) {
                    int n = nb + wc * 64 + u * 16 + c;
                    vt[((size_t)b * C_DIM + m) * N_DIM + n] = f2bf(acc[t][u][r] + bi);
                }
            }
    } else if (MODE == 1) {
        int hh = bo >> 6;            // BM=64 => one head per block
        int bh = b * NHEAD + hh;
        unsigned short* Ts = (unsigned short*)smem;   // [128 n][64 d] swz, 16KB
        __syncthreads();
        #pragma unroll
        for (int t = 0; t < 2; ++t)
            #pragma unroll
            for (int r = 0; r < 4; ++r) {
                int ml = wr * 32 + t * 16 + g * 4 + r;   // d
                float bi = bias[bo + ml];
                #pragma unroll
                for (int u = 0; u < 4; ++u) {
                    int nl = wc * 64 + u * 16 + c;
                    *(unsigned short*)((char*)Ts + nl * 128 + ((ml * 2) ^ ((nl & 7) << 4))) =
                        f2bf((acc[t][u][r] + bi) * escale);
                }
            }
        __syncthreads();
        unsigned short* qt = (unsigned short*)outp;
        #pragma unroll
        for (int i = 0; i < 4; ++i) {
            int idx = tid + i * 256;     // 1024 chunks = 128 rows x 8x16B
            int row = idx >> 3, ch = idx & 7;
            bf16x8 v = *(const bf16x8*)((char*)Ts + row * 128 + ((ch * 16) ^ ((row & 7) << 4)));
            *(bf16x8*)&qt[((size_t)bh * N_DIM + nb + row) * HDIM + ch * 8] = v;
        }
    } else {
        float* outf = (float*)outp;
        #pragma unroll
        for (int t = 0; t < 2; ++t)
            #pragma unroll
            for (int r = 0; r < 4; ++r) {
                int m = bo + wr * 32 + t * 16 + g * 4 + r;
                float bi = bias[m];
                #pragma unroll
                for (int u = 0; u < 4; ++u) {
                    int n = nb + wc * 64 + u * 16 + c;
                    size_t off = ((size_t)b * C_DIM + m) * N_DIM + n;
                    outf[off] = acc[t][u][r] + bi + res[off];
                }
            }
    }
}

// ---------------------------------------------------------------------------
// Barrier-free MFMA bf16 flash attention (swapped-operand form).
// K/V fragments load DIRECTLY from global (L2-resident; 64B-coalesced per
// instruction). Only wave-private P/O strip lives in LDS. No __syncthreads.
// Qt/Kt: bf16 [bh][n][d]; Vt: bf16 [b][c][n] (== [bh][d][n]); at: bf16 [b][n][c].
// ---------------------------------------------------------------------------
__global__ __launch_bounds__(256) void attn_kernel(const unsigned short* __restrict__ Qt,
                                                   const unsigned short* __restrict__ Kt,
                                                   const unsigned short* __restrict__ Vt,
                                                   unsigned short* __restrict__ at) {
    __shared__ char smem[8192];      // 4 waves x 2KB wave-private P/O strip

    int q0 = blockIdx.x * 64;
    int bh = blockIdx.y;
    int b = bh >> 3, hh = bh & 7;
    int tid = threadIdx.x;
    int L = tid & 63, w = tid >> 6;
    int g = L >> 4, c = L & 15;

    const unsigned short* Qh = Qt + (size_t)bh * N_DIM * HDIM;
    const unsigned short* Kh = Kt + (size_t)bh * N_DIM * HDIM;
    const unsigned short* Vh = Vt + (size_t)bh * HDIM * N_DIM;

    // ---- Q fragments (B-operand): q = q0+16w+c, k(d) = g*8+e+32ks ----
    bf16x8 qf[2];
    #pragma unroll
    for (int ks = 0; ks < 2; ++ks)
        qf[ks] = *(const bf16x8*)&Qh[(size_t)(q0 + w * 16 + c) * HDIM + g * 8 + ks * 32];

    // wave-private strip base (rows indexed by c, XOR-swizzled)
    int prow = w * 16 + c;
    int psw = (prow & 7) << 4;
    char* pb = smem + prow * 128;

    f32x4 oacc[4];
    #pragma unroll
    for (int t = 0; t < 4; ++t) oacc[t] = f32x4{0.f, 0.f, 0.f, 0.f};
    float m_r = -INFINITY, l_r = 0.f;

    for (int kt = 0; kt < N_DIM / 64; ++kt) {
        int k0 = kt * 64;
        // ---- direct global fragment loads (16 x dwordx4, 64B-coalesced) ----
        bf16x8 kf[4][2], vf[4][2];
        #pragma unroll
        for (int t = 0; t < 4; ++t)
            #pragma unroll
            for (int ks = 0; ks < 2; ++ks) {
                kf[t][ks] = *(const bf16x8*)&Kh[(size_t)(k0 + t * 16 + c) * HDIM + g * 8 + ks * 32];
                vf[t][ks] = *(const bf16x8*)&Vh[(size_t)(t * 16 + c) * N_DIM + k0 + g * 8 + ks * 32];
            }

        // ---- S^T = K Q^T : D[kpos=16t+4g+r][q=16w+c] ----
        f32x4 sacc[4];
        #pragma unroll
        for (int t = 0; t < 4; ++t) sacc[t] = f32x4{0.f, 0.f, 0.f, 0.f};
        __builtin_amdgcn_s_setprio(1);
        #pragma unroll
        for (int ks = 0; ks < 2; ++ks)
            #pragma unroll
            for (int t = 0; t < 4; ++t)
                sacc[t] = __builtin_amdgcn_mfma_f32_16x16x32_bf16(kf[t][ks], qf[ks], sacc[t], 0, 0, 0);
        __builtin_amdgcn_s_setprio(0);

        // ---- softmax over kpos (exp2 domain): in-lane 16 + 2 shfl ----
        float mloc = fmaxf(
            fmaxf(fmaxf(fmaxf(sacc[0][0], sacc[0][1]), fmaxf(sacc[0][2], sacc[0][3])),
                  fmaxf(fmaxf(sacc[1][0], sacc[1][1]), fmaxf(sacc[1][2], sacc[1][3]))),
            fmaxf(fmaxf(fmaxf(sacc[2][0], sacc[2][1]), fmaxf(sacc[2][2], sacc[2][3])),
                  fmaxf(fmaxf(sacc[3][0], sacc[3][1]), fmaxf(sacc[3][2], sacc[3][3]))));
        mloc = fmaxf(mloc, __shfl_xor(mloc, 16));
        mloc = fmaxf(mloc, __shfl_xor(mloc, 32));
        if (!__all(mloc - m_r <= 6.0f)) {     // T13 defer-max
            float mn = fmaxf(m_r, mloc);
            float fac = exp2f(m_r - mn);
            m_r = mn;
            l_r *= fac;
            #pragma unroll
            for (int t = 0; t < 4; ++t) oacc[t] = oacc[t] * fac;
        }
        float rs = 0.f;
        unsigned pk[4][2];
        #pragma unroll
        for (int t = 0; t < 4; ++t) {
            float p0 = exp2f(sacc[t][0] - m_r);
            float p1 = exp2f(sacc[t][1] - m_r);
            float p2 = exp2f(sacc[t][2] - m_r);
            float p3 = exp2f(sacc[t][3] - m_r);
            rs += (p0 + p1) + (p2 + p3);
            pk[t][0] = (unsigned)f2bf(p0) | ((unsigned)f2bf(p1) << 16);
            pk[t][1] = (unsigned)f2bf(p2) | ((unsigned)f2bf(p3) << 16);
        }
        rs += __shfl_xor(rs, 16);
        rs += __shfl_xor(rs, 32);
        l_r += rs;

        // ---- P^T strip (wave-private, intra-wave ordered, no barrier) ----
        #pragma unroll
        for (int t = 0; t < 4; ++t)
            *(unsigned long long*)(pb + ((t * 32 + g * 8) ^ psw)) =
                (unsigned long long)pk[t][0] | ((unsigned long long)pk[t][1] << 32);
        asm volatile("" ::: "memory");   // keep ds_read after ds_write

        // ---- O^T += V^T P^T : D[d=16t+4g+r][q=16w+c] ----
        __builtin_amdgcn_s_setprio(1);
        #pragma unroll
        for (int ks = 0; ks < 2; ++ks) {
            bf16x8 pf = *(const bf16x8*)(pb + ((ks * 64 + g * 16) ^ psw));
            #pragma unroll
            for (int t = 0; t < 4; ++t)
                oacc[t] = __builtin_amdgcn_mfma_f32_16x16x32_bf16(vf[t][ks], pf, oacc[t], 0, 0, 0);
        }
        __builtin_amdgcn_s_setprio(0);
    }

    // ---- epilogue (wave-private through the same strip) ----
    float oinv = 1.f / l_r;
    asm volatile("" ::: "memory");
    #pragma unroll
    for (int t = 0; t < 4; ++t) {
        unsigned lo = (unsigned)f2bf(oacc[t][0] * oinv) |
                      ((unsigned)f2bf(oacc[t][1] * oinv) << 16);
        unsigned hi = (unsigned)f2bf(oacc[t][2] * oinv) |
                      ((unsigned)f2bf(oacc[t][3] * oinv) << 16);
        *(unsigned long long*)(pb + ((t * 32 + g * 8) ^ psw)) =
            (unsigned long long)lo | ((unsigned long long)hi << 32);
    }
    asm volatile("" ::: "memory");
    char* wbase = smem + w * 2048;       // wave's 16 rows
    #pragma unroll
    for (int i = 0; i < 2; ++i) {
        int idx = L + i * 64;            // 128 chunks = 16 rows x 8x16B
        int row = idx >> 3, ch = idx & 7;
        bf16x8 v = *(const bf16x8*)(wbase + row * 128 + ((ch * 16) ^ ((row & 7) << 4)));
        *(bf16x8*)&at[((size_t)(b * N_DIM + q0 + w * 16 + row)) * C_DIM + hh * HDIM + ch * 8] = v;
    }
}

// ---------------------------------------------------------------------------
extern "C" void kernel_launch(void* const* d_in, const int* in_sizes, int n_in,
                              void* d_out, int out_size, void* d_ws, size_t ws_size,
                              hipStream_t stream) {
    (void)in_sizes; (void)n_in; (void)out_size; (void)ws_size;
    const float* x     = (const float*)d_in[0];
    const float* gam   = (const float*)d_in[1];
    const float* bet   = (const float*)d_in[2];
    const float* q_w   = (const float*)d_in[3];
    const float* q_b   = (const float*)d_in[4];
    const float* k_w   = (const float*)d_in[5];
    const float* k_b   = (const float*)d_in[6];
    const float* v_w   = (const float*)d_in[7];
    const float* v_b   = (const float*)d_in[8];
    const float* p_w   = (const float*)d_in[9];
    const float* p_b   = (const float*)d_in[10];
    float* out = (float*)d_out;

    const size_t MB = 1 << 20;
    char* wsb = (char*)d_ws;
    unsigned short* ht  = (unsigned short*)(wsb);              // 8 MB  [8192][512]
    unsigned short* wqb = (unsigned short*)(wsb + 8 * MB);     // 4 x 512KB contiguous
    unsigned short* wkb = (unsigned short*)(wsb + 8 * MB + 512 * 1024);
    unsigned short* wvb = (unsigned short*)(wsb + 9 * MB);
    unsigned short* wpb = (unsigned short*)(wsb + 9 * MB + 512 * 1024);
    float*          stats = (float*)(wsb + 10 * MB);           // 1 KB
    unsigned short* qt  = (unsigned short*)(wsb + 11 * MB);    // 8 MB [bh][n][d]
    unsigned short* kt  = (unsigned short*)(wsb + 19 * MB);    // 8 MB
    unsigned short* vt  = (unsigned short*)(wsb + 27 * MB);    // 8 MB [b][c][n]
    unsigned short* at  = (unsigned short*)(wsb + 35 * MB);    // 8 MB [b][n][c]

    gn_stats<<<B_DIM * NGRP, 256, 0, stream>>>(x, stats);
    gn_apply_t<<<dim3(N_DIM / 64, C_DIM / 64, B_DIM), 256, 0, stream>>>(x, stats, gam, bet, ht);

    cast4_bf16<<<dim3(128, 4), 256, 0, stream>>>(q_w, k_w, v_w, p_w, wqb);

    const float escale = 0.044194173824159216f * 1.4426950408889634f;  // scale*log2(e)
    dim3 cgrid(B_DIM * N_DIM / 128, C_DIM / 64);
    conv_mfma<1><<<cgrid, 256, 0, stream>>>(wqb, q_b, ht, nullptr, qt, escale);
    conv_mfma<1><<<cgrid, 256, 0, stream>>>(wkb, k_b, ht, nullptr, kt, 1.0f);
    conv_mfma<0><<<cgrid, 256, 0, stream>>>(wvb, v_b, ht, nullptr, vt, 1.0f);

    attn_kernel<<<dim3(N_DIM / 64, B_DIM * NHEAD), 256, 0, stream>>>(qt, kt, vt, at);

    conv_mfma<2><<<cgrid, 256, 0, stream>>>(wpb, p_b, at, x, out, 1.0f);
}

// Round 8
// 125.299 us; speedup vs baseline: 2.2401x; 2.2401x over previous
//
#include <hip/hip_runtime.h>
#include <hip/hip_bf16.h>
#include <math.h>

#define C_DIM 512
#define N_DIM 2048
#define B_DIM 4
#define NGRP 32
#define GCH 16          // channels per group
#define NHEAD 8
#define HDIM 64
#define EPSV 1e-6f

using f32x4  = __attribute__((ext_vector_type(4))) float;
using bf16x8 = __attribute__((ext_vector_type(8))) short;   // 8 bf16 raw bits (4 VGPRs)

// async global->LDS, 16B per lane; LDS dest = wave-uniform base + lane*16
#define GLL16(gp, lp) __builtin_amdgcn_global_load_lds( \
    (const __attribute__((address_space(1))) unsigned int*)(gp), \
    (__attribute__((address_space(3))) unsigned int*)(lp), 16, 0, 0)

static __device__ __forceinline__ unsigned short f2bf(float f) {
    union { __hip_bfloat16 h; unsigned short u; } cv;
    cv.h = __float2bfloat16(f);
    return cv.u;
}

// ---------------------------------------------------------------------------
// gn_stats: one block per (b,group); group slab contiguous (bg*32768 floats).
// ---------------------------------------------------------------------------
__global__ __launch_bounds__(256) void gn_stats(const float* __restrict__ x,
                                                float* __restrict__ stats) {
    const int GSZ = GCH * N_DIM;            // 32768
    int bg = blockIdx.x;
    const float4* x4 = (const float4*)(x + (size_t)bg * GSZ);
    int tid = threadIdx.x;

    float s = 0.f, ss = 0.f;
    #pragma unroll
    for (int it = 0; it < GSZ / 4 / 256; ++it) {
        float4 v = x4[tid + it * 256];
        s  += v.x + v.y + v.z + v.w;
        ss += v.x * v.x + v.y * v.y + v.z * v.z + v.w * v.w;
    }
    __shared__ float rs[256], rss[256];
    rs[tid] = s; rss[tid] = ss;
    __syncthreads();
    for (int off = 128; off > 0; off >>= 1) {
        if (tid < off) { rs[tid] += rs[tid + off]; rss[tid] += rss[tid + off]; }
        __syncthreads();
    }
    if (tid == 0) {
        float mean = rs[0] * (1.f / GSZ);
        float var  = rss[0] * (1.f / GSZ) - mean * mean;
        stats[bg * 2]     = mean;
        stats[bg * 2 + 1] = rsqrtf(var + EPSV);
    }
}

// ---------------------------------------------------------------------------
// gn_apply_t: x [b][c][n] fp32 -> ht [(b*n)][c] bf16 (normalized, transposed).
// ---------------------------------------------------------------------------
__global__ __launch_bounds__(256) void gn_apply_t(const float* __restrict__ x,
                                                  const float* __restrict__ stats,
                                                  const float* __restrict__ gamma,
                                                  const float* __restrict__ beta,
                                                  unsigned short* __restrict__ ht) {
    __shared__ char smem[8192];     // [64 n][64 c] bf16, rows 128B, XOR-swizzled
    int n0 = blockIdx.x * 64, c0 = blockIdx.y * 64, b = blockIdx.z;
    int tid = threadIdx.x;
    #pragma unroll
    for (int it = 0; it < 4; ++it) {
        int idx = tid + it * 256;
        int ci = idx >> 4, n4 = (idx & 15) << 2;
        int cg = c0 + ci, grp = cg >> 4;
        float mean = stats[(b * NGRP + grp) * 2];
        float rstd = stats[(b * NGRP + grp) * 2 + 1];
        float ga = gamma[cg] * rstd, be = beta[cg] - mean * ga;
        float4 v = *(const float4*)&x[((size_t)b * C_DIM + cg) * N_DIM + n0 + n4];
        float vals[4] = {v.x, v.y, v.z, v.w};
        #pragma unroll
        for (int j = 0; j < 4; ++j) {
            int nl = n4 + j;
            *(unsigned short*)(smem + nl * 128 + ((ci * 2) ^ ((nl & 7) << 4))) =
                f2bf(vals[j] * ga + be);
        }
    }
    __syncthreads();
    #pragma unroll
    for (int i = 0; i < 2; ++i) {
        int idx = tid + i * 256;       // 512 chunks = 64 rows x 8x16B
        int row = idx >> 3, ch = idx & 7;
        bf16x8 v = *(const bf16x8*)(smem + row * 128 + ((ch * 16) ^ ((row & 7) << 4)));
        *(bf16x8*)&ht[((size_t)(b * N_DIM + n0 + row)) * C_DIM + c0 + ch * 8] = v;
    }
}

// ---------------------------------------------------------------------------
// cast4: fp32 -> bf16 for the four 512x512 weights in one launch.
// ---------------------------------------------------------------------------
__global__ __launch_bounds__(256) void cast4_bf16(const float* __restrict__ s0,
                                                  const float* __restrict__ s1,
                                                  const float* __restrict__ s2,
                                                  const float* __restrict__ s3,
                                                  unsigned short* __restrict__ dst) {
    int which = blockIdx.y;
    const float* src = (which == 0) ? s0 : (which == 1) ? s1 : (which == 2) ? s2 : s3;
    size_t idx = (size_t)blockIdx.x * 256 + threadIdx.x;
    const float4* s4 = (const float4*)src;
    float4 a = s4[idx * 2], b = s4[idx * 2 + 1];
    bf16x8 o;
    o[0] = (short)f2bf(a.x); o[1] = (short)f2bf(a.y);
    o[2] = (short)f2bf(a.z); o[3] = (short)f2bf(a.w);
    o[4] = (short)f2bf(b.x); o[5] = (short)f2bf(b.y);
    o[6] = (short)f2bf(b.z); o[7] = (short)f2bf(b.w);
    *(bf16x8*)&dst[(size_t)which * 262144 + idx * 8] = o;
}

// ---------------------------------------------------------------------------
// conv_mfma: D[o][bn] = sum_c W[o][c] * ht[bn][c]  (+bias, modes below)
// Tile BM=64(o) x BN=128(bn) x BK=64. 4 waves, each 32x64.
// MODE 0: out bf16 natural [b][c][n]         (V conv)
// MODE 1: out bf16 [bh][n][d], *escale       (Q/K convs; one head per block)
// MODE 2: out fp32 [b][c][n] + res           (proj conv)
// ---------------------------------------------------------------------------
template <int MODE>
__global__ __launch_bounds__(256) void conv_mfma(const unsigned short* __restrict__ Wb,
                                                 const float* __restrict__ bias,
                                                 const unsigned short* __restrict__ Bsrc,
                                                 const float* __restrict__ res,
                                                 void* __restrict__ outp,
                                                 float escale) {
    __shared__ char smem[24576];
    unsigned short* As = (unsigned short*)smem;           // [64 o][64 k] swz, 8KB
    unsigned short* Bs = (unsigned short*)(smem + 8192);  // [128 n][64 k] swz, 16KB

    int bn0 = blockIdx.x * 128;      // flattened b*N + n
    int bo  = blockIdx.y * 64;
    int tid = threadIdx.x;
    int L = tid & 63, w = tid >> 6;
    int g = L >> 4, c = L & 15;
    int wr = w >> 1, wc = w & 1;

    f32x4 acc[2][4];
    #pragma unroll
    for (int t = 0; t < 2; ++t)
        #pragma unroll
        for (int u = 0; u < 4; ++u) acc[t][u] = f32x4{0.f, 0.f, 0.f, 0.f};

    for (int k0 = 0; k0 < C_DIM; k0 += 64) {
        #pragma unroll
        for (int i = 0; i < 2; ++i) {
            int j = w * 2 + i;
            int ra = j * 8 + (L >> 3);
            int sl = (L & 7) ^ (ra & 7);
            GLL16(Wb + (size_t)(bo + ra) * C_DIM + k0 + sl * 8, (char*)As + j * 1024);
        }
        #pragma unroll
        for (int i = 0; i < 4; ++i) {
            int j = w * 4 + i;
            int rb = j * 8 + (L >> 3);
            int sl = (L & 7) ^ (rb & 7);
            GLL16(Bsrc + (size_t)(bn0 + rb) * C_DIM + k0 + sl * 8, (char*)Bs + j * 1024);
        }
        __syncthreads();

        bf16x8 af[2][2], bfr[4][2];
        #pragma unroll
        for (int t = 0; t < 2; ++t) {
            int row = wr * 32 + t * 16 + c;
            #pragma unroll
            for (int ks = 0; ks < 2; ++ks)
                af[t][ks] = *(const bf16x8*)((char*)As + row * 128 +
                                             ((g * 16 + ks * 64) ^ ((row & 7) << 4)));
        }
        #pragma unroll
        for (int u = 0; u < 4; ++u) {
            int row = wc * 64 + u * 16 + c;
            #pragma unroll
            for (int ks = 0; ks < 2; ++ks)
                bfr[u][ks] = *(const bf16x8*)((char*)Bs + row * 128 +
                                              ((g * 16 + ks * 64) ^ ((row & 7) << 4)));
        }
        #pragma unroll
        for (int ks = 0; ks < 2; ++ks)
            #pragma unroll
            for (int t = 0; t < 2; ++t)
                #pragma unroll
                for (int u = 0; u < 4; ++u)
                    acc[t][u] = __builtin_amdgcn_mfma_f32_16x16x32_bf16(
                        af[t][ks], bfr[u][ks], acc[t][u], 0, 0, 0);
        __syncthreads();
    }

    int b  = bn0 >> 11;              // N_DIM = 2048
    int nb = bn0 & (N_DIM - 1);

    if (MODE == 0) {
        unsigned short* vt = (unsigned short*)outp;
        #pragma unroll
        for (int t = 0; t < 2; ++t)
            #pragma unroll
            for (int r = 0; r < 4; ++r) {
                int m = bo + wr * 32 + t * 16 + g * 4 + r;
                float bi = bias[m];
                #pragma unroll
                for (int u = 0; u < 4; ++u) {
                    int n = nb + wc * 64 + u * 16 + c;
                    vt[((size_t)b * C_DIM + m) * N_DIM + n] = f2bf(acc[t][u][r] + bi);
                }
            }
    } else if (MODE == 1) {
        int hh = bo >> 6;            // BM=64 => one head per block
        int bh = b * NHEAD + hh;
        unsigned short* Ts = (unsigned short*)smem;   // [128 n][64 d] swz, 16KB
        __syncthreads();
        #pragma unroll
        for (int t = 0; t < 2; ++t)
            #pragma unroll
            for (int r = 0; r < 4; ++r) {
                int ml = wr * 32 + t * 16 + g * 4 + r;   // d
                float bi = bias[bo + ml];
                #pragma unroll
                for (int u = 0; u < 4; ++u) {
                    int nl = wc * 64 + u * 16 + c;
                    *(unsigned short*)((char*)Ts + nl * 128 + ((ml * 2) ^ ((nl & 7) << 4))) =
                        f2bf((acc[t][u][r] + bi) * escale);
                }
            }
        __syncthreads();
        unsigned short* qt = (unsigned short*)outp;
        #pragma unroll
        for (int i = 0; i < 4; ++i) {
            int idx = tid + i * 256;     // 1024 chunks = 128 rows x 8x16B
            int row = idx >> 3, ch = idx & 7;
            bf16x8 v = *(const bf16x8*)((char*)Ts + row * 128 + ((ch * 16) ^ ((row & 7) << 4)));
            *(bf16x8*)&qt[((size_t)bh * N_DIM + nb + row) * HDIM + ch * 8] = v;
        }
    } else {
        float* outf = (float*)outp;
        #pragma unroll
        for (int t = 0; t < 2; ++t)
            #pragma unroll
            for (int r = 0; r < 4; ++r) {
                int m = bo + wr * 32 + t * 16 + g * 4 + r;
                float bi = bias[m];
                #pragma unroll
                for (int u = 0; u < 4; ++u) {
                    int n = nb + wc * 64 + u * 16 + c;
                    size_t off = ((size_t)b * C_DIM + m) * N_DIM + n;
                    outf[off] = acc[t][u][r] + bi + res[off];
                }
            }
    }
}

// ---------------------------------------------------------------------------
// MFMA bf16 flash attention, swapped-operand form. 8 waves, QBLK=128.
// grid (16, 32) = 512 blocks = exactly 2/CU.
// K/V staged via global_load_lds, double-buffered; ONE barrier per iter.
// Wave-private P/O strips overlay the Q region (wave w's strip == the Q rows
// only wave w reads). Qt/Kt: bf16 [bh][n][d]; Vt: bf16 [bh][d][n];
// at: bf16 [b][n][c].
// ---------------------------------------------------------------------------
__global__ __launch_bounds__(512, 4) void attn_kernel(const unsigned short* __restrict__ Qt,
                                                      const unsigned short* __restrict__ Kt,
                                                      const unsigned short* __restrict__ Vt,
                                                      unsigned short* __restrict__ at) {
    __shared__ char smem[49152];
    char* PQ = smem;                       // 16KB: Q staging, then P/O strips
    // K/V double buffers: buf b at smem + 16384 + b*16384 (K 8KB | V 8KB)

    int q0 = blockIdx.x * 128;
    int bh = blockIdx.y;
    int b = bh >> 3, hh = bh & 7;
    int tid = threadIdx.x;
    int L = tid & 63, w = tid >> 6;        // 8 waves
    int g = L >> 4, c = L & 15;

    const unsigned short* Qh = Qt + (size_t)bh * N_DIM * HDIM;
    const unsigned short* Kh = Kt + (size_t)bh * N_DIM * HDIM;
    const unsigned short* Vh = Vt + (size_t)bh * HDIM * N_DIM;

    // ---- prologue: stage Q (16 x 1KB) + K/V tile 0 into buf0, all async ----
    #pragma unroll
    for (int i = 0; i < 2; ++i) {
        int j = w * 2 + i;
        int row = j * 8 + (L >> 3);        // 0..127
        int sl = (L & 7) ^ (row & 7);
        GLL16(Qh + (size_t)(q0 + row) * HDIM + sl * 8, PQ + j * 1024);
    }
    {
        int row = w * 8 + (L >> 3);        // 0..63
        int sl = (L & 7) ^ (row & 7);
        GLL16(Kh + (size_t)row * HDIM + sl * 8, smem + 16384 + w * 1024);
        GLL16(Vh + (size_t)row * N_DIM + sl * 8, smem + 24576 + w * 1024);
    }
    __syncthreads();                       // drains vmcnt -> Q + tile0 ready

    // ---- hoist Q fragments; strip base doubles as P/O strip ----
    int prow = w * 16 + c;                 // q-local row
    int psw = (c & 7) << 4;
    char* pb = PQ + prow * 128;
    bf16x8 qf[2];
    #pragma unroll
    for (int ks = 0; ks < 2; ++ks)
        qf[ks] = *(const bf16x8*)(pb + ((g * 16 + ks * 64) ^ psw));

    f32x4 oacc[4];
    #pragma unroll
    for (int t = 0; t < 4; ++t) oacc[t] = f32x4{0.f, 0.f, 0.f, 0.f};
    float m_r = -INFINITY, l_r = 0.f;

    for (int kt = 0; kt < N_DIM / 64; ++kt) {
        int cur = kt & 1;
        char* Ksb = smem + 16384 + cur * 16384;
        char* Vsb = Ksb + 8192;
        // ---- issue next tile's staging FIRST (hides under compute) ----
        if (kt < N_DIM / 64 - 1) {
            int k0n = (kt + 1) * 64;
            int row = w * 8 + (L >> 3);
            int sl = (L & 7) ^ (row & 7);
            char* Ksn = smem + 16384 + (cur ^ 1) * 16384;
            GLL16(Kh + (size_t)(k0n + row) * HDIM + sl * 8, Ksn + w * 1024);
            GLL16(Vh + (size_t)row * N_DIM + k0n + sl * 8, Ksn + 8192 + w * 1024);
        }

        // ---- S^T = K Q^T : D[kpos=16t+4g+r][q=16w+c] ----
        f32x4 sacc[4];
        #pragma unroll
        for (int t = 0; t < 4; ++t) sacc[t] = f32x4{0.f, 0.f, 0.f, 0.f};
        __builtin_amdgcn_s_setprio(1);
        #pragma unroll
        for (int t = 0; t < 4; ++t) {
            int row = t * 16 + c;
            #pragma unroll
            for (int ks = 0; ks < 2; ++ks) {
                bf16x8 kf = *(const bf16x8*)(Ksb + row * 128 +
                                             ((g * 16 + ks * 64) ^ ((row & 7) << 4)));
                sacc[t] = __builtin_amdgcn_mfma_f32_16x16x32_bf16(kf, qf[ks], sacc[t], 0, 0, 0);
            }
        }
        __builtin_amdgcn_s_setprio(0);

        // ---- softmax over kpos (exp2 domain): in-lane 16 + 2 shfl ----
        float mloc = fmaxf(
            fmaxf(fmaxf(fmaxf(sacc[0][0], sacc[0][1]), fmaxf(sacc[0][2], sacc[0][3])),
                  fmaxf(fmaxf(sacc[1][0], sacc[1][1]), fmaxf(sacc[1][2], sacc[1][3]))),
            fmaxf(fmaxf(fmaxf(sacc[2][0], sacc[2][1]), fmaxf(sacc[2][2], sacc[2][3])),
                  fmaxf(fmaxf(sacc[3][0], sacc[3][1]), fmaxf(sacc[3][2], sacc[3][3]))));
        mloc = fmaxf(mloc, __shfl_xor(mloc, 16));
        mloc = fmaxf(mloc, __shfl_xor(mloc, 32));
        if (!__all(mloc - m_r <= 6.0f)) {     // T13 defer-max
            float mn = fmaxf(m_r, mloc);
            float fac = exp2f(m_r - mn);
            m_r = mn;
            l_r *= fac;
            #pragma unroll
            for (int t = 0; t < 4; ++t) oacc[t] = oacc[t] * fac;
        }
        float rs = 0.f;
        unsigned pk[4][2];
        #pragma unroll
        for (int t = 0; t < 4; ++t) {
            float p0 = exp2f(sacc[t][0] - m_r);
            float p1 = exp2f(sacc[t][1] - m_r);
            float p2 = exp2f(sacc[t][2] - m_r);
            float p3 = exp2f(sacc[t][3] - m_r);
            rs += (p0 + p1) + (p2 + p3);
            pk[t][0] = (unsigned)f2bf(p0) | ((unsigned)f2bf(p1) << 16);
            pk[t][1] = (unsigned)f2bf(p2) | ((unsigned)f2bf(p3) << 16);
        }
        rs += __shfl_xor(rs, 16);
        rs += __shfl_xor(rs, 32);
        l_r += rs;

        // ---- P^T strip (wave-private, intra-wave DS ordering only) ----
        #pragma unroll
        for (int t = 0; t < 4; ++t)
            *(unsigned long long*)(pb + ((t * 32 + g * 8) ^ psw)) =
                (unsigned long long)pk[t][0] | ((unsigned long long)pk[t][1] << 32);

        // ---- O^T += V^T P^T : D[d=16t+4g+r][q=16w+c] ----
        __builtin_amdgcn_s_setprio(1);
        #pragma unroll
        for (int ks = 0; ks < 2; ++ks) {
            bf16x8 pf = *(const bf16x8*)(pb + ((ks * 64 + g * 16) ^ psw));
            #pragma unroll
            for (int t = 0; t < 4; ++t) {
                int vrow = t * 16 + c;
                bf16x8 vf = *(const bf16x8*)(Vsb + vrow * 128 +
                                             ((g * 16 + ks * 64) ^ ((vrow & 7) << 4)));
                oacc[t] = __builtin_amdgcn_mfma_f32_16x16x32_bf16(vf, pf, oacc[t], 0, 0, 0);
            }
        }
        __builtin_amdgcn_s_setprio(0);

        __syncthreads();   // all waves done with buf[cur]; buf[cur^1] staged
    }

    // ---- epilogue: O through wave-private strip, coalesced bf16 store ----
    float oinv = 1.f / l_r;
    #pragma unroll
    for (int t = 0; t < 4; ++t) {
        unsigned lo = (unsigned)f2bf(oacc[t][0] * oinv) |
                      ((unsigned)f2bf(oacc[t][1] * oinv) << 16);
        unsigned hi = (unsigned)f2bf(oacc[t][2] * oinv) |
                      ((unsigned)f2bf(oacc[t][3] * oinv) << 16);
        *(unsigned long long*)(pb + ((t * 32 + g * 8) ^ psw)) =
            (unsigned long long)lo | ((unsigned long long)hi << 32);
    }
    char* wbase = PQ + w * 2048;           // wave's 16 rows
    #pragma unroll
    for (int i = 0; i < 2; ++i) {
        int idx = L + i * 64;              // 128 chunks = 16 rows x 8x16B
        int row = idx >> 3, ch = idx & 7;
        bf16x8 v = *(const bf16x8*)(wbase + row * 128 + ((ch * 16) ^ ((row & 7) << 4)));
        *(bf16x8*)&at[((size_t)(b * N_DIM + q0 + w * 16 + row)) * C_DIM + hh * HDIM + ch * 8] = v;
    }
}

// ---------------------------------------------------------------------------
extern "C" void kernel_launch(void* const* d_in, const int* in_sizes, int n_in,
                              void* d_out, int out_size, void* d_ws, size_t ws_size,
                              hipStream_t stream) {
    (void)in_sizes; (void)n_in; (void)out_size; (void)ws_size;
    const float* x     = (const float*)d_in[0];
    const float* gam   = (const float*)d_in[1];
    const float* bet   = (const float*)d_in[2];
    const float* q_w   = (const float*)d_in[3];
    const float* q_b   = (const float*)d_in[4];
    const float* k_w   = (const float*)d_in[5];
    const float* k_b   = (const float*)d_in[6];
    const float* v_w   = (const float*)d_in[7];
    const float* v_b   = (const float*)d_in[8];
    const float* p_w   = (const float*)d_in[9];
    const float* p_b   = (const float*)d_in[10];
    float* out = (float*)d_out;

    const size_t MB = 1 << 20;
    char* wsb = (char*)d_ws;
    unsigned short* ht  = (unsigned short*)(wsb);              // 8 MB  [8192][512]
    unsigned short* wqb = (unsigned short*)(wsb + 8 * MB);     // 4 x 512KB contiguous
    unsigned short* wkb = (unsigned short*)(wsb + 8 * MB + 512 * 1024);
    unsigned short* wvb = (unsigned short*)(wsb + 9 * MB);
    unsigned short* wpb = (unsigned short*)(wsb + 9 * MB + 512 * 1024);
    float*          stats = (float*)(wsb + 10 * MB);           // 1 KB
    unsigned short* qt  = (unsigned short*)(wsb + 11 * MB);    // 8 MB [bh][n][d]
    unsigned short* kt  = (unsigned short*)(wsb + 19 * MB);    // 8 MB
    unsigned short* vt  = (unsigned short*)(wsb + 27 * MB);    // 8 MB [b][c][n]
    unsigned short* at  = (unsigned short*)(wsb + 35 * MB);    // 8 MB [b][n][c]

    gn_stats<<<B_DIM * NGRP, 256, 0, stream>>>(x, stats);
    gn_apply_t<<<dim3(N_DIM / 64, C_DIM / 64, B_DIM), 256, 0, stream>>>(x, stats, gam, bet, ht);

    cast4_bf16<<<dim3(128, 4), 256, 0, stream>>>(q_w, k_w, v_w, p_w, wqb);

    const float escale = 0.044194173824159216f * 1.4426950408889634f;  // scale*log2(e)
    dim3 cgrid(B_DIM * N_DIM / 128, C_DIM / 64);
    conv_mfma<1><<<cgrid, 256, 0, stream>>>(wqb, q_b, ht, nullptr, qt, escale);
    conv_mfma<1><<<cgrid, 256, 0, stream>>>(wkb, k_b, ht, nullptr, kt, 1.0f);
    conv_mfma<0><<<cgrid, 256, 0, stream>>>(wvb, v_b, ht, nullptr, vt, 1.0f);

    attn_kernel<<<dim3(N_DIM / 128, B_DIM * NHEAD), 512, 0, stream>>>(qt, kt, vt, at);

    conv_mfma<2><<<cgrid, 256, 0, stream>>>(wpb, p_b, at, x, out, 1.0f);
}

// Round 9
// 121.152 us; speedup vs baseline: 2.3167x; 1.0342x over previous
//
#include <hip/hip_runtime.h>
#include <hip/hip_bf16.h>
#include <math.h>

#define C_DIM 512
#define N_DIM 2048
#define B_DIM 4
#define NGRP 32
#define GCH 16          // channels per group
#define NHEAD 8
#define HDIM 64
#define EPSV 1e-6f

using f32x4  = __attribute__((ext_vector_type(4))) float;
using bf16x8 = __attribute__((ext_vector_type(8))) short;   // 8 bf16 raw bits (4 VGPRs)

// async global->LDS, 16B per lane; LDS dest = wave-uniform base + lane*16
#define GLL16(gp, lp) __builtin_amdgcn_global_load_lds( \
    (const __attribute__((address_space(1))) unsigned int*)(gp), \
    (__attribute__((address_space(3))) unsigned int*)(lp), 16, 0, 0)

// pack high-16 (truncated bf16) of two f32s: lo16 = a, hi16 = b
#define BFPACK(a, b) __builtin_amdgcn_perm(__float_as_uint(b), __float_as_uint(a), 0x07060302u)

static __device__ __forceinline__ unsigned short f2bf(float f) {
    union { __hip_bfloat16 h; unsigned short u; } cv;
    cv.h = __float2bfloat16(f);
    return cv.u;
}

// ---------------------------------------------------------------------------
// gn_stats: one block per (b,group); group slab contiguous (bg*32768 floats).
// ---------------------------------------------------------------------------
__global__ __launch_bounds__(256) void gn_stats(const float* __restrict__ x,
                                                float* __restrict__ stats) {
    const int GSZ = GCH * N_DIM;            // 32768
    int bg = blockIdx.x;
    const float4* x4 = (const float4*)(x + (size_t)bg * GSZ);
    int tid = threadIdx.x;

    float s = 0.f, ss = 0.f;
    #pragma unroll
    for (int it = 0; it < GSZ / 4 / 256; ++it) {
        float4 v = x4[tid + it * 256];
        s  += v.x + v.y + v.z + v.w;
        ss += v.x * v.x + v.y * v.y + v.z * v.z + v.w * v.w;
    }
    __shared__ float rs[256], rss[256];
    rs[tid] = s; rss[tid] = ss;
    __syncthreads();
    for (int off = 128; off > 0; off >>= 1) {
        if (tid < off) { rs[tid] += rs[tid + off]; rss[tid] += rss[tid + off]; }
        __syncthreads();
    }
    if (tid == 0) {
        float mean = rs[0] * (1.f / GSZ);
        float var  = rss[0] * (1.f / GSZ) - mean * mean;
        stats[bg * 2]     = mean;
        stats[bg * 2 + 1] = rsqrtf(var + EPSV);
    }
}

// ---------------------------------------------------------------------------
// gn_apply_t: x [b][c][n] fp32 -> ht [(b*n)][c] bf16 (normalized, transposed).
// ---------------------------------------------------------------------------
__global__ __launch_bounds__(256) void gn_apply_t(const float* __restrict__ x,
                                                  const float* __restrict__ stats,
                                                  const float* __restrict__ gamma,
                                                  const float* __restrict__ beta,
                                                  unsigned short* __restrict__ ht) {
    __shared__ char smem[8192];     // [64 n][64 c] bf16, rows 128B, XOR-swizzled
    int n0 = blockIdx.x * 64, c0 = blockIdx.y * 64, b = blockIdx.z;
    int tid = threadIdx.x;
    #pragma unroll
    for (int it = 0; it < 4; ++it) {
        int idx = tid + it * 256;
        int ci = idx >> 4, n4 = (idx & 15) << 2;
        int cg = c0 + ci, grp = cg >> 4;
        float mean = stats[(b * NGRP + grp) * 2];
        float rstd = stats[(b * NGRP + grp) * 2 + 1];
        float ga = gamma[cg] * rstd, be = beta[cg] - mean * ga;
        float4 v = *(const float4*)&x[((size_t)b * C_DIM + cg) * N_DIM + n0 + n4];
        float vals[4] = {v.x, v.y, v.z, v.w};
        #pragma unroll
        for (int j = 0; j < 4; ++j) {
            int nl = n4 + j;
            *(unsigned short*)(smem + nl * 128 + ((ci * 2) ^ ((nl & 7) << 4))) =
                f2bf(vals[j] * ga + be);
        }
    }
    __syncthreads();
    #pragma unroll
    for (int i = 0; i < 2; ++i) {
        int idx = tid + i * 256;       // 512 chunks = 64 rows x 8x16B
        int row = idx >> 3, ch = idx & 7;
        bf16x8 v = *(const bf16x8*)(smem + row * 128 + ((ch * 16) ^ ((row & 7) << 4)));
        *(bf16x8*)&ht[((size_t)(b * N_DIM + n0 + row)) * C_DIM + c0 + ch * 8] = v;
    }
}

// ---------------------------------------------------------------------------
// cast4: fp32 -> bf16 for the four 512x512 weights in one launch.
// ---------------------------------------------------------------------------
__global__ __launch_bounds__(256) void cast4_bf16(const float* __restrict__ s0,
                                                  const float* __restrict__ s1,
                                                  const float* __restrict__ s2,
                                                  const float* __restrict__ s3,
                                                  unsigned short* __restrict__ dst) {
    int which = blockIdx.y;
    const float* src = (which == 0) ? s0 : (which == 1) ? s1 : (which == 2) ? s2 : s3;
    size_t idx = (size_t)blockIdx.x * 256 + threadIdx.x;
    const float4* s4 = (const float4*)src;
    float4 a = s4[idx * 2], b = s4[idx * 2 + 1];
    bf16x8 o;
    o[0] = (short)f2bf(a.x); o[1] = (short)f2bf(a.y);
    o[2] = (short)f2bf(a.z); o[3] = (short)f2bf(a.w);
    o[4] = (short)f2bf(b.x); o[5] = (short)f2bf(b.y);
    o[6] = (short)f2bf(b.z); o[7] = (short)f2bf(b.w);
    *(bf16x8*)&dst[(size_t)which * 262144 + idx * 8] = o;
}

// ---------------------------------------------------------------------------
// conv_qkv: fused Q/K/V pointwise convs. D_w[o][n] = sum_c W_w[o][c]*ht[bn][c].
// Tile BM=64(o) x BN=64(bn) x BK=64; 4 waves each 32x32 per weight.
// Bs staged ONCE per k-step, shared by 3 weight A-tiles.
// Q -> qt [bh][n][d] *escale; K -> kt [bh][n][d]; V -> vt [b][c][n].
// grid (B*N/64, C/64), 256 threads.
// ---------------------------------------------------------------------------
__global__ __launch_bounds__(256) void conv_qkv(const unsigned short* __restrict__ Wall,
                                                const float* __restrict__ q_b,
                                                const float* __restrict__ k_b,
                                                const float* __restrict__ v_b,
                                                const unsigned short* __restrict__ ht,
                                                unsigned short* __restrict__ qt,
                                                unsigned short* __restrict__ kt,
                                                unsigned short* __restrict__ vt,
                                                float escale) {
    __shared__ char smem[32768];     // Bs 8KB | As_q 8KB | As_k 8KB | As_v 8KB

    int bn0 = blockIdx.x * 64;       // flattened b*N + n
    int bo  = blockIdx.y * 64;
    int tid = threadIdx.x;
    int L = tid & 63, w = tid >> 6;
    int g = L >> 4, c = L & 15;
    int wr = w >> 1, wc = w & 1;

    f32x4 acc[3][2][2];
    #pragma unroll
    for (int w3 = 0; w3 < 3; ++w3)
        #pragma unroll
        for (int t = 0; t < 2; ++t)
            #pragma unroll
            for (int u = 0; u < 2; ++u) acc[w3][t][u] = f32x4{0.f, 0.f, 0.f, 0.f};

    // wave-uniform staging assignment: w0 -> Bs, w1..3 -> As for weight w-1
    const unsigned short* sbase;
    char* ldsb;
    if (w == 0) { sbase = ht + (size_t)bn0 * C_DIM; ldsb = smem; }
    else { sbase = Wall + (size_t)(w - 1) * 262144 + (size_t)bo * C_DIM; ldsb = smem + w * 8192; }

    for (int k0 = 0; k0 < C_DIM; k0 += 64) {
        #pragma unroll
        for (int i = 0; i < 8; ++i) {
            int row = i * 8 + (L >> 3);
            int sl = (L & 7) ^ (row & 7);
            GLL16(sbase + (size_t)row * C_DIM + k0 + sl * 8, ldsb + i * 1024);
        }
        __syncthreads();

        bf16x8 bfr[2][2];
        #pragma unroll
        for (int u = 0; u < 2; ++u) {
            int row = wc * 32 + u * 16 + c;
            #pragma unroll
            for (int ks = 0; ks < 2; ++ks)
                bfr[u][ks] = *(const bf16x8*)(smem + row * 128 +
                                              ((g * 16 + ks * 64) ^ ((row & 7) << 4)));
        }
        #pragma unroll
        for (int w3 = 0; w3 < 3; ++w3) {
            char* As = smem + 8192 + w3 * 8192;
            bf16x8 af[2][2];
            #pragma unroll
            for (int t = 0; t < 2; ++t) {
                int row = wr * 32 + t * 16 + c;
                #pragma unroll
                for (int ks = 0; ks < 2; ++ks)
                    af[t][ks] = *(const bf16x8*)(As + row * 128 +
                                                 ((g * 16 + ks * 64) ^ ((row & 7) << 4)));
            }
            #pragma unroll
            for (int ks = 0; ks < 2; ++ks)
                #pragma unroll
                for (int t = 0; t < 2; ++t)
                    #pragma unroll
                    for (int u = 0; u < 2; ++u)
                        acc[w3][t][u] = __builtin_amdgcn_mfma_f32_16x16x32_bf16(
                            af[t][ks], bfr[u][ks], acc[w3][t][u], 0, 0, 0);
        }
        __syncthreads();
    }

    int b  = bn0 >> 11;              // N_DIM = 2048
    int nb = bn0 & (N_DIM - 1);
    int hh = bo >> 6;
    int bh = b * NHEAD + hh;

    // ---- V epilogue: natural [b][c][n] bf16 ----
    #pragma unroll
    for (int t = 0; t < 2; ++t)
        #pragma unroll
        for (int r = 0; r < 4; ++r) {
            int m = bo + wr * 32 + t * 16 + g * 4 + r;
            float bi = v_b[m];
            #pragma unroll
            for (int u = 0; u < 2; ++u) {
                int n = nb + wc * 32 + u * 16 + c;
                vt[((size_t)b * C_DIM + m) * N_DIM + n] = f2bf(acc[2][t][u][r] + bi);
            }
        }

    // ---- Q then K epilogues: transpose through Ts (reuse Bs region) ----
    char* Ts = smem;                 // [64 n][64 d] swz, 8KB
    #pragma unroll
    for (int pass = 0; pass < 2; ++pass) {
        const float* bias = pass ? k_b : q_b;
        float esc = pass ? 1.0f : escale;
        unsigned short* dst = pass ? kt : qt;
        __syncthreads();
        #pragma unroll
        for (int t = 0; t < 2; ++t)
            #pragma unroll
            for (int r = 0; r < 4; ++r) {
                int ml = wr * 32 + t * 16 + g * 4 + r;   // d
                float bi = bias[bo + ml];
                #pragma unroll
                for (int u = 0; u < 2; ++u) {
                    int nl = wc * 32 + u * 16 + c;
                    *(unsigned short*)(Ts + nl * 128 + ((ml * 2) ^ ((nl & 7) << 4))) =
                        f2bf((acc[pass][t][u][r] + bi) * esc);
                }
            }
        __syncthreads();
        #pragma unroll
        for (int i = 0; i < 2; ++i) {
            int idx = tid + i * 256;     // 512 chunks = 64 rows x 8x16B
            int row = idx >> 3, ch = idx & 7;
            bf16x8 v = *(const bf16x8*)(Ts + row * 128 + ((ch * 16) ^ ((row & 7) << 4)));
            *(bf16x8*)&dst[((size_t)bh * N_DIM + nb + row) * HDIM + ch * 8] = v;
        }
    }
}

// ---------------------------------------------------------------------------
// conv_mfma MODE 2 (proj): out fp32 [b][c][n] + residual.
// Tile BM=64 x BN=128 x BK=64. 4 waves, each 32x64. (Unchanged from R8.)
// ---------------------------------------------------------------------------
__global__ __launch_bounds__(256) void conv_proj(const unsigned short* __restrict__ Wb,
                                                 const float* __restrict__ bias,
                                                 const unsigned short* __restrict__ Bsrc,
                                                 const float* __restrict__ res,
                                                 float* __restrict__ outf) {
    __shared__ char smem[24576];
    int bn0 = blockIdx.x * 128;
    int bo  = blockIdx.y * 64;
    int tid = threadIdx.x;
    int L = tid & 63, w = tid >> 6;
    int g = L >> 4, c = L & 15;
    int wr = w >> 1, wc = w & 1;

    f32x4 acc[2][4];
    #pragma unroll
    for (int t = 0; t < 2; ++t)
        #pragma unroll
        for (int u = 0; u < 4; ++u) acc[t][u] = f32x4{0.f, 0.f, 0.f, 0.f};

    for (int k0 = 0; k0 < C_DIM; k0 += 64) {
        #pragma unroll
        for (int i = 0; i < 2; ++i) {
            int j = w * 2 + i;
            int ra = j * 8 + (L >> 3);
            int sl = (L & 7) ^ (ra & 7);
            GLL16(Wb + (size_t)(bo + ra) * C_DIM + k0 + sl * 8, smem + j * 1024);
        }
        #pragma unroll
        for (int i = 0; i < 4; ++i) {
            int j = w * 4 + i;
            int rb = j * 8 + (L >> 3);
            int sl = (L & 7) ^ (rb & 7);
            GLL16(Bsrc + (size_t)(bn0 + rb) * C_DIM + k0 + sl * 8, smem + 8192 + j * 1024);
        }
        __syncthreads();

        bf16x8 af[2][2], bfr[4][2];
        #pragma unroll
        for (int t = 0; t < 2; ++t) {
            int row = wr * 32 + t * 16 + c;
            #pragma unroll
            for (int ks = 0; ks < 2; ++ks)
                af[t][ks] = *(const bf16x8*)(smem + row * 128 +
                                             ((g * 16 + ks * 64) ^ ((row & 7) << 4)));
        }
        #pragma unroll
        for (int u = 0; u < 4; ++u) {
            int row = wc * 64 + u * 16 + c;
            #pragma unroll
            for (int ks = 0; ks < 2; ++ks)
                bfr[u][ks] = *(const bf16x8*)(smem + 8192 + row * 128 +
                                              ((g * 16 + ks * 64) ^ ((row & 7) << 4)));
        }
        #pragma unroll
        for (int ks = 0; ks < 2; ++ks)
            #pragma unroll
            for (int t = 0; t < 2; ++t)
                #pragma unroll
                for (int u = 0; u < 4; ++u)
                    acc[t][u] = __builtin_amdgcn_mfma_f32_16x16x32_bf16(
                        af[t][ks], bfr[u][ks], acc[t][u], 0, 0, 0);
        __syncthreads();
    }

    int b  = bn0 >> 11;
    int nb = bn0 & (N_DIM - 1);
    #pragma unroll
    for (int t = 0; t < 2; ++t)
        #pragma unroll
        for (int r = 0; r < 4; ++r) {
            int m = bo + wr * 32 + t * 16 + g * 4 + r;
            float bi = bias[m];
            #pragma unroll
            for (int u = 0; u < 4; ++u) {
                int n = nb + wc * 64 + u * 16 + c;
                size_t off = ((size_t)b * C_DIM + m) * N_DIM + n;
                outf[off] = acc[t][u][r] + bi + res[off];
            }
        }
}

// ---------------------------------------------------------------------------
// MFMA bf16 flash attention, swapped-operand form. 8 waves, QBLK=128.
// K/V staged via global_load_lds, double-buffered; ONE barrier per iter.
// P/O packing via v_perm truncation; max3-grouped reductions.
// ---------------------------------------------------------------------------
__global__ __launch_bounds__(512, 4) void attn_kernel(const unsigned short* __restrict__ Qt,
                                                      const unsigned short* __restrict__ Kt,
                                                      const unsigned short* __restrict__ Vt,
                                                      unsigned short* __restrict__ at) {
    __shared__ char smem[49152];
    char* PQ = smem;                       // 16KB: Q staging, then P/O strips

    int q0 = blockIdx.x * 128;
    int bh = blockIdx.y;
    int b = bh >> 3, hh = bh & 7;
    int tid = threadIdx.x;
    int L = tid & 63, w = tid >> 6;        // 8 waves
    int g = L >> 4, c = L & 15;

    const unsigned short* Qh = Qt + (size_t)bh * N_DIM * HDIM;
    const unsigned short* Kh = Kt + (size_t)bh * N_DIM * HDIM;
    const unsigned short* Vh = Vt + (size_t)bh * HDIM * N_DIM;

    // ---- prologue: stage Q (16 x 1KB) + K/V tile 0 into buf0, all async ----
    #pragma unroll
    for (int i = 0; i < 2; ++i) {
        int j = w * 2 + i;
        int row = j * 8 + (L >> 3);        // 0..127
        int sl = (L & 7) ^ (row & 7);
        GLL16(Qh + (size_t)(q0 + row) * HDIM + sl * 8, PQ + j * 1024);
    }
    {
        int row = w * 8 + (L >> 3);        // 0..63
        int sl = (L & 7) ^ (row & 7);
        GLL16(Kh + (size_t)row * HDIM + sl * 8, smem + 16384 + w * 1024);
        GLL16(Vh + (size_t)row * N_DIM + sl * 8, smem + 24576 + w * 1024);
    }
    __syncthreads();                       // drains vmcnt -> Q + tile0 ready

    // ---- hoist Q fragments; strip base doubles as P/O strip ----
    int prow = w * 16 + c;                 // q-local row
    int psw = (c & 7) << 4;
    char* pb = PQ + prow * 128;
    bf16x8 qf[2];
    #pragma unroll
    for (int ks = 0; ks < 2; ++ks)
        qf[ks] = *(const bf16x8*)(pb + ((g * 16 + ks * 64) ^ psw));

    f32x4 oacc[4];
    #pragma unroll
    for (int t = 0; t < 4; ++t) oacc[t] = f32x4{0.f, 0.f, 0.f, 0.f};
    float m_r = -INFINITY, l_r = 0.f;

    for (int kt = 0; kt < N_DIM / 64; ++kt) {
        int cur = kt & 1;
        char* Ksb = smem + 16384 + cur * 16384;
        char* Vsb = Ksb + 8192;
        // ---- issue next tile's staging FIRST (hides under compute) ----
        if (kt < N_DIM / 64 - 1) {
            int k0n = (kt + 1) * 64;
            int row = w * 8 + (L >> 3);
            int sl = (L & 7) ^ (row & 7);
            char* Ksn = smem + 16384 + (cur ^ 1) * 16384;
            GLL16(Kh + (size_t)(k0n + row) * HDIM + sl * 8, Ksn + w * 1024);
            GLL16(Vh + (size_t)row * N_DIM + k0n + sl * 8, Ksn + 8192 + w * 1024);
        }

        // ---- S^T = K Q^T : D[kpos=16t+4g+r][q=16w+c] ----
        f32x4 sacc[4];
        #pragma unroll
        for (int t = 0; t < 4; ++t) sacc[t] = f32x4{0.f, 0.f, 0.f, 0.f};
        __builtin_amdgcn_s_setprio(1);
        #pragma unroll
        for (int t = 0; t < 4; ++t) {
            int row = t * 16 + c;
            #pragma unroll
            for (int ks = 0; ks < 2; ++ks) {
                bf16x8 kf = *(const bf16x8*)(Ksb + row * 128 +
                                             ((g * 16 + ks * 64) ^ ((row & 7) << 4)));
                sacc[t] = __builtin_amdgcn_mfma_f32_16x16x32_bf16(kf, qf[ks], sacc[t], 0, 0, 0);
            }
        }
        __builtin_amdgcn_s_setprio(0);

        // ---- softmax over kpos (exp2 domain), max3-grouped reduce ----
        float t0 = fmaxf(fmaxf(sacc[0][0], sacc[0][1]), sacc[0][2]);
        float t1 = fmaxf(fmaxf(sacc[0][3], sacc[1][0]), sacc[1][1]);
        float t2 = fmaxf(fmaxf(sacc[1][2], sacc[1][3]), sacc[2][0]);
        float t3 = fmaxf(fmaxf(sacc[2][1], sacc[2][2]), sacc[2][3]);
        float t4 = fmaxf(fmaxf(sacc[3][0], sacc[3][1]), sacc[3][2]);
        float u0 = fmaxf(fmaxf(t0, t1), t2);
        float u1 = fmaxf(fmaxf(t3, t4), sacc[3][3]);
        float mloc = fmaxf(u0, u1);
        mloc = fmaxf(mloc, __shfl_xor(mloc, 16));
        mloc = fmaxf(mloc, __shfl_xor(mloc, 32));
        if (!__all(mloc - m_r <= 6.0f)) {     // T13 defer-max
            float mn = fmaxf(m_r, mloc);
            float fac = exp2f(m_r - mn);
            m_r = mn;
            l_r *= fac;
            #pragma unroll
            for (int t = 0; t < 4; ++t) oacc[t] = oacc[t] * fac;
        }
        float rs = 0.f;
        unsigned pk[4][2];
        #pragma unroll
        for (int t = 0; t < 4; ++t) {
            float p0 = exp2f(sacc[t][0] - m_r);
            float p1 = exp2f(sacc[t][1] - m_r);
            float p2 = exp2f(sacc[t][2] - m_r);
            float p3 = exp2f(sacc[t][3] - m_r);
            rs += (p0 + p1) + (p2 + p3);
            pk[t][0] = BFPACK(p0, p1);        // truncation pack
            pk[t][1] = BFPACK(p2, p3);
        }
        rs += __shfl_xor(rs, 16);
        rs += __shfl_xor(rs, 32);
        l_r += rs;

        // ---- P^T strip (wave-private, intra-wave DS ordering only) ----
        #pragma unroll
        for (int t = 0; t < 4; ++t)
            *(unsigned long long*)(pb + ((t * 32 + g * 8) ^ psw)) =
                (unsigned long long)pk[t][0] | ((unsigned long long)pk[t][1] << 32);

        // ---- O^T += V^T P^T : D[d=16t+4g+r][q=16w+c] ----
        __builtin_amdgcn_s_setprio(1);
        #pragma unroll
        for (int ks = 0; ks < 2; ++ks) {
            bf16x8 pf = *(const bf16x8*)(pb + ((ks * 64 + g * 16) ^ psw));
            #pragma unroll
            for (int t = 0; t < 4; ++t) {
                int vrow = t * 16 + c;
                bf16x8 vf = *(const bf16x8*)(Vsb + vrow * 128 +
                                             ((g * 16 + ks * 64) ^ ((vrow & 7) << 4)));
                oacc[t] = __builtin_amdgcn_mfma_f32_16x16x32_bf16(vf, pf, oacc[t], 0, 0, 0);
            }
        }
        __builtin_amdgcn_s_setprio(0);

        __syncthreads();   // all waves done with buf[cur]; buf[cur^1] staged
    }

    // ---- epilogue: O through wave-private strip, coalesced bf16 store ----
    float oinv = 1.f / l_r;
    #pragma unroll
    for (int t = 0; t < 4; ++t) {
        unsigned lo = BFPACK(oacc[t][0] * oinv, oacc[t][1] * oinv);
        unsigned hi = BFPACK(oacc[t][2] * oinv, oacc[t][3] * oinv);
        *(unsigned long long*)(pb + ((t * 32 + g * 8) ^ psw)) =
            (unsigned long long)lo | ((unsigned long long)hi << 32);
    }
    char* wbase = PQ + w * 2048;           // wave's 16 rows
    #pragma unroll
    for (int i = 0; i < 2; ++i) {
        int idx = L + i * 64;              // 128 chunks = 16 rows x 8x16B
        int row = idx >> 3, ch = idx & 7;
        bf16x8 v = *(const bf16x8*)(wbase + row * 128 + ((ch * 16) ^ ((row & 7) << 4)));
        *(bf16x8*)&at[((size_t)(b * N_DIM + q0 + w * 16 + row)) * C_DIM + hh * HDIM + ch * 8] = v;
    }
}

// ---------------------------------------------------------------------------
extern "C" void kernel_launch(void* const* d_in, const int* in_sizes, int n_in,
                              void* d_out, int out_size, void* d_ws, size_t ws_size,
                              hipStream_t stream) {
    (void)in_sizes; (void)n_in; (void)out_size; (void)ws_size;
    const float* x     = (const float*)d_in[0];
    const float* gam   = (const float*)d_in[1];
    const float* bet   = (const float*)d_in[2];
    const float* q_w   = (const float*)d_in[3];
    const float* q_b   = (const float*)d_in[4];
    const float* k_w   = (const float*)d_in[5];
    const float* k_b   = (const float*)d_in[6];
    const float* v_w   = (const float*)d_in[7];
    const float* v_b   = (const float*)d_in[8];
    const float* p_w   = (const float*)d_in[9];
    const float* p_b   = (const float*)d_in[10];
    float* out = (float*)d_out;

    const size_t MB = 1 << 20;
    char* wsb = (char*)d_ws;
    unsigned short* ht  = (unsigned short*)(wsb);              // 8 MB  [8192][512]
    unsigned short* wqb = (unsigned short*)(wsb + 8 * MB);     // 4 x 512KB contiguous (q,k,v,p)
    unsigned short* wpb = (unsigned short*)(wsb + 9 * MB + 512 * 1024);
    float*          stats = (float*)(wsb + 10 * MB);           // 1 KB
    unsigned short* qt  = (unsigned short*)(wsb + 11 * MB);    // 8 MB [bh][n][d]
    unsigned short* kt  = (unsigned short*)(wsb + 19 * MB);    // 8 MB
    unsigned short* vt  = (unsigned short*)(wsb + 27 * MB);    // 8 MB [b][c][n]
    unsigned short* at  = (unsigned short*)(wsb + 35 * MB);    // 8 MB [b][n][c]

    gn_stats<<<B_DIM * NGRP, 256, 0, stream>>>(x, stats);
    gn_apply_t<<<dim3(N_DIM / 64, C_DIM / 64, B_DIM), 256, 0, stream>>>(x, stats, gam, bet, ht);

    cast4_bf16<<<dim3(128, 4), 256, 0, stream>>>(q_w, k_w, v_w, p_w, wqb);

    const float escale = 0.044194173824159216f * 1.4426950408889634f;  // scale*log2(e)
    conv_qkv<<<dim3(B_DIM * N_DIM / 64, C_DIM / 64), 256, 0, stream>>>(
        wqb, q_b, k_b, v_b, ht, qt, kt, vt, escale);

    attn_kernel<<<dim3(N_DIM / 128, B_DIM * NHEAD), 512, 0, stream>>>(qt, kt, vt, at);

    conv_proj<<<dim3(B_DIM * N_DIM / 128, C_DIM / 64), 256, 0, stream>>>(wpb, p_b, at, x, out);
}

// Round 10
// 116.512 us; speedup vs baseline: 2.4090x; 1.0398x over previous
//
#include <hip/hip_runtime.h>
#include <hip/hip_bf16.h>
#include <math.h>

#define C_DIM 512
#define N_DIM 2048
#define B_DIM 4
#define NGRP 32
#define GCH 16          // channels per group
#define NHEAD 8
#define HDIM 64
#define EPSV 1e-6f

using f32x4  = __attribute__((ext_vector_type(4))) float;
using bf16x8 = __attribute__((ext_vector_type(8))) short;   // 8 bf16 raw bits (4 VGPRs)

// async global->LDS, 16B per lane; LDS dest = wave-uniform base + lane*16
#define GLL16(gp, lp) __builtin_amdgcn_global_load_lds( \
    (const __attribute__((address_space(1))) unsigned int*)(gp), \
    (__attribute__((address_space(3))) unsigned int*)(lp), 16, 0, 0)

// pack high-16 (truncated bf16) of two f32s: lo16 = a, hi16 = b
#define BFPACK(a, b) __builtin_amdgcn_perm(__float_as_uint(b), __float_as_uint(a), 0x07060302u)

static __device__ __forceinline__ unsigned short f2bf(float f) {
    union { __hip_bfloat16 h; unsigned short u; } cv;
    cv.h = __float2bfloat16(f);
    return cv.u;
}

// ---------------------------------------------------------------------------
// gn_stats: one block per (b,group); group slab contiguous (bg*32768 floats).
// ---------------------------------------------------------------------------
__global__ __launch_bounds__(256) void gn_stats(const float* __restrict__ x,
                                                float* __restrict__ stats) {
    const int GSZ = GCH * N_DIM;            // 32768
    int bg = blockIdx.x;
    const float4* x4 = (const float4*)(x + (size_t)bg * GSZ);
    int tid = threadIdx.x;

    float s = 0.f, ss = 0.f;
    #pragma unroll
    for (int it = 0; it < GSZ / 4 / 256; ++it) {
        float4 v = x4[tid + it * 256];
        s  += v.x + v.y + v.z + v.w;
        ss += v.x * v.x + v.y * v.y + v.z * v.z + v.w * v.w;
    }
    __shared__ float rs[256], rss[256];
    rs[tid] = s; rss[tid] = ss;
    __syncthreads();
    for (int off = 128; off > 0; off >>= 1) {
        if (tid < off) { rs[tid] += rs[tid + off]; rss[tid] += rss[tid + off]; }
        __syncthreads();
    }
    if (tid == 0) {
        float mean = rs[0] * (1.f / GSZ);
        float var  = rss[0] * (1.f / GSZ) - mean * mean;
        stats[bg * 2]     = mean;
        stats[bg * 2 + 1] = rsqrtf(var + EPSV);
    }
}

// ---------------------------------------------------------------------------
// gn_apply_t: x [b][c][n] fp32 -> ht [(b*n)][c] bf16 (normalized, transposed).
// ---------------------------------------------------------------------------
__global__ __launch_bounds__(256) void gn_apply_t(const float* __restrict__ x,
                                                  const float* __restrict__ stats,
                                                  const float* __restrict__ gamma,
                                                  const float* __restrict__ beta,
                                                  unsigned short* __restrict__ ht) {
    __shared__ char smem[8192];     // [64 n][64 c] bf16, rows 128B, XOR-swizzled
    int n0 = blockIdx.x * 64, c0 = blockIdx.y * 64, b = blockIdx.z;
    int tid = threadIdx.x;
    #pragma unroll
    for (int it = 0; it < 4; ++it) {
        int idx = tid + it * 256;
        int ci = idx >> 4, n4 = (idx & 15) << 2;
        int cg = c0 + ci, grp = cg >> 4;
        float mean = stats[(b * NGRP + grp) * 2];
        float rstd = stats[(b * NGRP + grp) * 2 + 1];
        float ga = gamma[cg] * rstd, be = beta[cg] - mean * ga;
        float4 v = *(const float4*)&x[((size_t)b * C_DIM + cg) * N_DIM + n0 + n4];
        float vals[4] = {v.x, v.y, v.z, v.w};
        #pragma unroll
        for (int j = 0; j < 4; ++j) {
            int nl = n4 + j;
            *(unsigned short*)(smem + nl * 128 + ((ci * 2) ^ ((nl & 7) << 4))) =
                f2bf(vals[j] * ga + be);
        }
    }
    __syncthreads();
    #pragma unroll
    for (int i = 0; i < 2; ++i) {
        int idx = tid + i * 256;       // 512 chunks = 64 rows x 8x16B
        int row = idx >> 3, ch = idx & 7;
        bf16x8 v = *(const bf16x8*)(smem + row * 128 + ((ch * 16) ^ ((row & 7) << 4)));
        *(bf16x8*)&ht[((size_t)(b * N_DIM + n0 + row)) * C_DIM + c0 + ch * 8] = v;
    }
}

// ---------------------------------------------------------------------------
// cast4: fp32 -> bf16 for the four 512x512 weights in one launch.
// ---------------------------------------------------------------------------
__global__ __launch_bounds__(256) void cast4_bf16(const float* __restrict__ s0,
                                                  const float* __restrict__ s1,
                                                  const float* __restrict__ s2,
                                                  const float* __restrict__ s3,
                                                  unsigned short* __restrict__ dst) {
    int which = blockIdx.y;
    const float* src = (which == 0) ? s0 : (which == 1) ? s1 : (which == 2) ? s2 : s3;
    size_t idx = (size_t)blockIdx.x * 256 + threadIdx.x;
    const float4* s4 = (const float4*)src;
    float4 a = s4[idx * 2], b = s4[idx * 2 + 1];
    bf16x8 o;
    o[0] = (short)f2bf(a.x); o[1] = (short)f2bf(a.y);
    o[2] = (short)f2bf(a.z); o[3] = (short)f2bf(a.w);
    o[4] = (short)f2bf(b.x); o[5] = (short)f2bf(b.y);
    o[6] = (short)f2bf(b.z); o[7] = (short)f2bf(b.w);
    *(bf16x8*)&dst[(size_t)which * 262144 + idx * 8] = o;
}

// ---------------------------------------------------------------------------
// conv_qkv: fused Q/K/V pointwise convs. (Unchanged from R9.)
// ---------------------------------------------------------------------------
__global__ __launch_bounds__(256) void conv_qkv(const unsigned short* __restrict__ Wall,
                                                const float* __restrict__ q_b,
                                                const float* __restrict__ k_b,
                                                const float* __restrict__ v_b,
                                                const unsigned short* __restrict__ ht,
                                                unsigned short* __restrict__ qt,
                                                unsigned short* __restrict__ kt,
                                                unsigned short* __restrict__ vt,
                                                float escale) {
    __shared__ char smem[32768];     // Bs 8KB | As_q 8KB | As_k 8KB | As_v 8KB

    int bn0 = blockIdx.x * 64;       // flattened b*N + n
    int bo  = blockIdx.y * 64;
    int tid = threadIdx.x;
    int L = tid & 63, w = tid >> 6;
    int g = L >> 4, c = L & 15;
    int wr = w >> 1, wc = w & 1;

    f32x4 acc[3][2][2];
    #pragma unroll
    for (int w3 = 0; w3 < 3; ++w3)
        #pragma unroll
        for (int t = 0; t < 2; ++t)
            #pragma unroll
            for (int u = 0; u < 2; ++u) acc[w3][t][u] = f32x4{0.f, 0.f, 0.f, 0.f};

    const unsigned short* sbase;
    char* ldsb;
    if (w == 0) { sbase = ht + (size_t)bn0 * C_DIM; ldsb = smem; }
    else { sbase = Wall + (size_t)(w - 1) * 262144 + (size_t)bo * C_DIM; ldsb = smem + w * 8192; }

    for (int k0 = 0; k0 < C_DIM; k0 += 64) {
        #pragma unroll
        for (int i = 0; i < 8; ++i) {
            int row = i * 8 + (L >> 3);
            int sl = (L & 7) ^ (row & 7);
            GLL16(sbase + (size_t)row * C_DIM + k0 + sl * 8, ldsb + i * 1024);
        }
        __syncthreads();

        bf16x8 bfr[2][2];
        #pragma unroll
        for (int u = 0; u < 2; ++u) {
            int row = wc * 32 + u * 16 + c;
            #pragma unroll
            for (int ks = 0; ks < 2; ++ks)
                bfr[u][ks] = *(const bf16x8*)(smem + row * 128 +
                                              ((g * 16 + ks * 64) ^ ((row & 7) << 4)));
        }
        #pragma unroll
        for (int w3 = 0; w3 < 3; ++w3) {
            char* As = smem + 8192 + w3 * 8192;
            bf16x8 af[2][2];
            #pragma unroll
            for (int t = 0; t < 2; ++t) {
                int row = wr * 32 + t * 16 + c;
                #pragma unroll
                for (int ks = 0; ks < 2; ++ks)
                    af[t][ks] = *(const bf16x8*)(As + row * 128 +
                                                 ((g * 16 + ks * 64) ^ ((row & 7) << 4)));
            }
            #pragma unroll
            for (int ks = 0; ks < 2; ++ks)
                #pragma unroll
                for (int t = 0; t < 2; ++t)
                    #pragma unroll
                    for (int u = 0; u < 2; ++u)
                        acc[w3][t][u] = __builtin_amdgcn_mfma_f32_16x16x32_bf16(
                            af[t][ks], bfr[u][ks], acc[w3][t][u], 0, 0, 0);
        }
        __syncthreads();
    }

    int b  = bn0 >> 11;              // N_DIM = 2048
    int nb = bn0 & (N_DIM - 1);
    int hh = bo >> 6;
    int bh = b * NHEAD + hh;

    #pragma unroll
    for (int t = 0; t < 2; ++t)
        #pragma unroll
        for (int r = 0; r < 4; ++r) {
            int m = bo + wr * 32 + t * 16 + g * 4 + r;
            float bi = v_b[m];
            #pragma unroll
            for (int u = 0; u < 2; ++u) {
                int n = nb + wc * 32 + u * 16 + c;
                vt[((size_t)b * C_DIM + m) * N_DIM + n] = f2bf(acc[2][t][u][r] + bi);
            }
        }

    char* Ts = smem;                 // [64 n][64 d] swz, 8KB
    #pragma unroll
    for (int pass = 0; pass < 2; ++pass) {
        const float* bias = pass ? k_b : q_b;
        float esc = pass ? 1.0f : escale;
        unsigned short* dst = pass ? kt : qt;
        __syncthreads();
        #pragma unroll
        for (int t = 0; t < 2; ++t)
            #pragma unroll
            for (int r = 0; r < 4; ++r) {
                int ml = wr * 32 + t * 16 + g * 4 + r;   // d
                float bi = bias[bo + ml];
                #pragma unroll
                for (int u = 0; u < 2; ++u) {
                    int nl = wc * 32 + u * 16 + c;
                    *(unsigned short*)(Ts + nl * 128 + ((ml * 2) ^ ((nl & 7) << 4))) =
                        f2bf((acc[pass][t][u][r] + bi) * esc);
                }
            }
        __syncthreads();
        #pragma unroll
        for (int i = 0; i < 2; ++i) {
            int idx = tid + i * 256;     // 512 chunks = 64 rows x 8x16B
            int row = idx >> 3, ch = idx & 7;
            bf16x8 v = *(const bf16x8*)(Ts + row * 128 + ((ch * 16) ^ ((row & 7) << 4)));
            *(bf16x8*)&dst[((size_t)bh * N_DIM + nb + row) * HDIM + ch * 8] = v;
        }
    }
}

// ---------------------------------------------------------------------------
// conv_proj: out fp32 [b][c][n] + residual. (Unchanged from R9.)
// ---------------------------------------------------------------------------
__global__ __launch_bounds__(256) void conv_proj(const unsigned short* __restrict__ Wb,
                                                 const float* __restrict__ bias,
                                                 const unsigned short* __restrict__ Bsrc,
                                                 const float* __restrict__ res,
                                                 float* __restrict__ outf) {
    __shared__ char smem[24576];
    int bn0 = blockIdx.x * 128;
    int bo  = blockIdx.y * 64;
    int tid = threadIdx.x;
    int L = tid & 63, w = tid >> 6;
    int g = L >> 4, c = L & 15;
    int wr = w >> 1, wc = w & 1;

    f32x4 acc[2][4];
    #pragma unroll
    for (int t = 0; t < 2; ++t)
        #pragma unroll
        for (int u = 0; u < 4; ++u) acc[t][u] = f32x4{0.f, 0.f, 0.f, 0.f};

    for (int k0 = 0; k0 < C_DIM; k0 += 64) {
        #pragma unroll
        for (int i = 0; i < 2; ++i) {
            int j = w * 2 + i;
            int ra = j * 8 + (L >> 3);
            int sl = (L & 7) ^ (ra & 7);
            GLL16(Wb + (size_t)(bo + ra) * C_DIM + k0 + sl * 8, smem + j * 1024);
        }
        #pragma unroll
        for (int i = 0; i < 4; ++i) {
            int j = w * 4 + i;
            int rb = j * 8 + (L >> 3);
            int sl = (L & 7) ^ (rb & 7);
            GLL16(Bsrc + (size_t)(bn0 + rb) * C_DIM + k0 + sl * 8, smem + 8192 + j * 1024);
        }
        __syncthreads();

        bf16x8 af[2][2], bfr[4][2];
        #pragma unroll
        for (int t = 0; t < 2; ++t) {
            int row = wr * 32 + t * 16 + c;
            #pragma unroll
            for (int ks = 0; ks < 2; ++ks)
                af[t][ks] = *(const bf16x8*)(smem + row * 128 +
                                             ((g * 16 + ks * 64) ^ ((row & 7) << 4)));
        }
        #pragma unroll
        for (int u = 0; u < 4; ++u) {
            int row = wc * 64 + u * 16 + c;
            #pragma unroll
            for (int ks = 0; ks < 2; ++ks)
                bfr[u][ks] = *(const bf16x8*)(smem + 8192 + row * 128 +
                                              ((g * 16 + ks * 64) ^ ((row & 7) << 4)));
        }
        #pragma unroll
        for (int ks = 0; ks < 2; ++ks)
            #pragma unroll
            for (int t = 0; t < 2; ++t)
                #pragma unroll
                for (int u = 0; u < 4; ++u)
                    acc[t][u] = __builtin_amdgcn_mfma_f32_16x16x32_bf16(
                        af[t][ks], bfr[u][ks], acc[t][u], 0, 0, 0);
        __syncthreads();
    }

    int b  = bn0 >> 11;
    int nb = bn0 & (N_DIM - 1);
    #pragma unroll
    for (int t = 0; t < 2; ++t)
        #pragma unroll
        for (int r = 0; r < 4; ++r) {
            int m = bo + wr * 32 + t * 16 + g * 4 + r;
            float bi = bias[m];
            #pragma unroll
            for (int u = 0; u < 4; ++u) {
                int n = nb + wc * 64 + u * 16 + c;
                size_t off = ((size_t)b * C_DIM + m) * N_DIM + n;
                outf[off] = acc[t][u][r] + bi + res[off];
            }
        }
}

// ---------------------------------------------------------------------------
// MFMA bf16 flash attention, swapped-operand form. 8 waves, QBLK=128.
// R10: hoisted LDS addresses, manual 2x unroll (literal buffer offsets),
// zero-shfl steady-state softmax (lane-local defer-max + deferred l-reduce).
// ---------------------------------------------------------------------------
__global__ __launch_bounds__(512, 4) void attn_kernel(const unsigned short* __restrict__ Qt,
                                                      const unsigned short* __restrict__ Kt,
                                                      const unsigned short* __restrict__ Vt,
                                                      unsigned short* __restrict__ at) {
    __shared__ char smem[49152];
    // [0,16K): Q staging -> P/O strips; [16K,32K): buf0 (K|V); [32K,48K): buf1

    int q0 = blockIdx.x * 128;
    int bh = blockIdx.y;
    int b = bh >> 3, hh = bh & 7;
    int tid = threadIdx.x;
    int L = tid & 63, w = tid >> 6;        // 8 waves
    int g = L >> 4, c = L & 15;

    const unsigned short* Qh = Qt + (size_t)bh * N_DIM * HDIM;
    const unsigned short* Kh = Kt + (size_t)bh * N_DIM * HDIM;
    const unsigned short* Vh = Vt + (size_t)bh * HDIM * N_DIM;

    // ---- prologue: stage Q (16 x 1KB) + K/V tile 0 into buf0, all async ----
    #pragma unroll
    for (int i = 0; i < 2; ++i) {
        int j = w * 2 + i;
        int row = j * 8 + (L >> 3);        // 0..127
        int sl = (L & 7) ^ (row & 7);
        GLL16(Qh + (size_t)(q0 + row) * HDIM + sl * 8, smem + j * 1024);
    }
    int srow = w * 8 + (L >> 3);           // staging row 0..63
    int ssl  = (L & 7) ^ (srow & 7);
    GLL16(Kh + (size_t)srow * HDIM + ssl * 8, smem + 16384 + w * 1024);
    GLL16(Vh + (size_t)srow * N_DIM + ssl * 8, smem + 24576 + w * 1024);
    __syncthreads();                       // drains vmcnt -> Q + tile0 ready

    // ---- hoisted addresses ----
    int csw = (c & 7) << 4;
    char* kb0 = smem + 16384 + c * 128 + ((g * 16) ^ csw);        // K frag ks=0
    char* kb1 = smem + 16384 + c * 128 + ((g * 16 + 64) ^ csw);   // K frag ks=1
    char* pb  = smem + (w * 16 + c) * 128;                        // wave-private strip
    char* pw0 = pb + ((g * 8) ^ csw);
    char* pw1 = pb + ((32 + g * 8) ^ csw);
    char* pw2 = pb + ((64 + g * 8) ^ csw);
    char* pw3 = pb + ((96 + g * 8) ^ csw);
    char* pr0 = pb + ((g * 16) ^ csw);
    char* pr1 = pb + ((64 + g * 16) ^ csw);

    // Q fragments from strip region (same addresses as pr0/pr1)
    bf16x8 qf[2];
    qf[0] = *(const bf16x8*)pr0;
    qf[1] = *(const bf16x8*)pr1;

    // staging global pointers -> tile 1
    const unsigned short* kgp = Kh + (size_t)(64 + srow) * HDIM + ssl * 8;
    const unsigned short* vgp = Vh + (size_t)srow * N_DIM + 64 + ssl * 8;

    f32x4 oacc[4];
    #pragma unroll
    for (int t = 0; t < 4; ++t) oacc[t] = f32x4{0.f, 0.f, 0.f, 0.f};
    float m_r = -INFINITY, l_part = 0.f;

    auto tile = [&](int BOFF) {
        // ---- S^T = K Q^T : D[kpos=16t+4g+r][q=16w+c] ----
        f32x4 sacc[4];
        #pragma unroll
        for (int t = 0; t < 4; ++t) sacc[t] = f32x4{0.f, 0.f, 0.f, 0.f};
        __builtin_amdgcn_s_setprio(1);
        #pragma unroll
        for (int t = 0; t < 4; ++t) {
            bf16x8 kf0 = *(const bf16x8*)(kb0 + BOFF + t * 2048);
            bf16x8 kf1 = *(const bf16x8*)(kb1 + BOFF + t * 2048);
            sacc[t] = __builtin_amdgcn_mfma_f32_16x16x32_bf16(kf0, qf[0], sacc[t], 0, 0, 0);
            sacc[t] = __builtin_amdgcn_mfma_f32_16x16x32_bf16(kf1, qf[1], sacc[t], 0, 0, 0);
        }
        __builtin_amdgcn_s_setprio(0);

        // ---- softmax over kpos (exp2 domain); zero-shfl steady state ----
        float t0 = fmaxf(fmaxf(sacc[0][0], sacc[0][1]), sacc[0][2]);
        float t1 = fmaxf(fmaxf(sacc[0][3], sacc[1][0]), sacc[1][1]);
        float t2 = fmaxf(fmaxf(sacc[1][2], sacc[1][3]), sacc[2][0]);
        float t3 = fmaxf(fmaxf(sacc[2][1], sacc[2][2]), sacc[2][3]);
        float t4 = fmaxf(fmaxf(sacc[3][0], sacc[3][1]), sacc[3][2]);
        float mloc = fmaxf(fmaxf(fmaxf(t0, t1), fmaxf(t2, t3)), fmaxf(t4, sacc[3][3]));
        if (!__all(mloc - m_r <= 6.0f)) {       // rare: row max grew
            mloc = fmaxf(mloc, __shfl_xor(mloc, 16));
            mloc = fmaxf(mloc, __shfl_xor(mloc, 32));
            float mn = fmaxf(m_r, mloc);
            float fac = exp2f(m_r - mn);
            m_r = mn;
            l_part *= fac;
            #pragma unroll
            for (int t = 0; t < 4; ++t) oacc[t] = oacc[t] * fac;
        }
        float rs = 0.f;
        unsigned pk[4][2];
        #pragma unroll
        for (int t = 0; t < 4; ++t) {
            float p0 = exp2f(sacc[t][0] - m_r);
            float p1 = exp2f(sacc[t][1] - m_r);
            float p2 = exp2f(sacc[t][2] - m_r);
            float p3 = exp2f(sacc[t][3] - m_r);
            rs += (p0 + p1) + (p2 + p3);
            pk[t][0] = BFPACK(p0, p1);
            pk[t][1] = BFPACK(p2, p3);
        }
        l_part += rs;                           // lane-local; reduced at end

        // ---- P^T strip (wave-private) ----
        *(unsigned long long*)pw0 = (unsigned long long)pk[0][0] | ((unsigned long long)pk[0][1] << 32);
        *(unsigned long long*)pw1 = (unsigned long long)pk[1][0] | ((unsigned long long)pk[1][1] << 32);
        *(unsigned long long*)pw2 = (unsigned long long)pk[2][0] | ((unsigned long long)pk[2][1] << 32);
        *(unsigned long long*)pw3 = (unsigned long long)pk[3][0] | ((unsigned long long)pk[3][1] << 32);

        // ---- O^T += V^T P^T ----
        __builtin_amdgcn_s_setprio(1);
        {
            bf16x8 pf0 = *(const bf16x8*)pr0;
            #pragma unroll
            for (int t = 0; t < 4; ++t) {
                bf16x8 vf = *(const bf16x8*)(kb0 + BOFF + 8192 + t * 2048);
                oacc[t] = __builtin_amdgcn_mfma_f32_16x16x32_bf16(vf, pf0, oacc[t], 0, 0, 0);
            }
            bf16x8 pf1 = *(const bf16x8*)pr1;
            #pragma unroll
            for (int t = 0; t < 4; ++t) {
                bf16x8 vf = *(const bf16x8*)(kb1 + BOFF + 8192 + t * 2048);
                oacc[t] = __builtin_amdgcn_mfma_f32_16x16x32_bf16(vf, pf1, oacc[t], 0, 0, 0);
            }
        }
        __builtin_amdgcn_s_setprio(0);
    };

    for (int i = 0; i < 16; ++i) {
        // body A: stage tile(2i+1) -> buf1, compute buf0
        GLL16(kgp, smem + 32768 + w * 1024);
        GLL16(vgp, smem + 40960 + w * 1024);
        kgp += 64 * HDIM;
        vgp += 64;
        tile(0);
        __syncthreads();
        // body B: stage tile(2i+2) -> buf0 (guarded), compute buf1
        if (i < 15) {
            GLL16(kgp, smem + 16384 + w * 1024);
            GLL16(vgp, smem + 24576 + w * 1024);
            kgp += 64 * HDIM;
            vgp += 64;
        }
        tile(16384);
        __syncthreads();
    }

    // ---- deferred l reduction + epilogue ----
    float l_r = l_part;
    l_r += __shfl_xor(l_r, 16);
    l_r += __shfl_xor(l_r, 32);
    float oinv = 1.f / l_r;
    {
        unsigned lo, hi;
        lo = BFPACK(oacc[0][0] * oinv, oacc[0][1] * oinv);
        hi = BFPACK(oacc[0][2] * oinv, oacc[0][3] * oinv);
        *(unsigned long long*)pw0 = (unsigned long long)lo | ((unsigned long long)hi << 32);
        lo = BFPACK(oacc[1][0] * oinv, oacc[1][1] * oinv);
        hi = BFPACK(oacc[1][2] * oinv, oacc[1][3] * oinv);
        *(unsigned long long*)pw1 = (unsigned long long)lo | ((unsigned long long)hi << 32);
        lo = BFPACK(oacc[2][0] * oinv, oacc[2][1] * oinv);
        hi = BFPACK(oacc[2][2] * oinv, oacc[2][3] * oinv);
        *(unsigned long long*)pw2 = (unsigned long long)lo | ((unsigned long long)hi << 32);
        lo = BFPACK(oacc[3][0] * oinv, oacc[3][1] * oinv);
        hi = BFPACK(oacc[3][2] * oinv, oacc[3][3] * oinv);
        *(unsigned long long*)pw3 = (unsigned long long)lo | ((unsigned long long)hi << 32);
    }
    char* wbase = smem + w * 2048;         // wave's 16 rows
    #pragma unroll
    for (int i = 0; i < 2; ++i) {
        int idx = L + i * 64;              // 128 chunks = 16 rows x 8x16B
        int row = idx >> 3, ch = idx & 7;
        bf16x8 v = *(const bf16x8*)(wbase + row * 128 + ((ch * 16) ^ ((row & 7) << 4)));
        *(bf16x8*)&at[((size_t)(b * N_DIM + q0 + w * 16 + row)) * C_DIM + hh * HDIM + ch * 8] = v;
    }
}

// ---------------------------------------------------------------------------
extern "C" void kernel_launch(void* const* d_in, const int* in_sizes, int n_in,
                              void* d_out, int out_size, void* d_ws, size_t ws_size,
                              hipStream_t stream) {
    (void)in_sizes; (void)n_in; (void)out_size; (void)ws_size;
    const float* x     = (const float*)d_in[0];
    const float* gam   = (const float*)d_in[1];
    const float* bet   = (const float*)d_in[2];
    const float* q_w   = (const float*)d_in[3];
    const float* q_b   = (const float*)d_in[4];
    const float* k_w   = (const float*)d_in[5];
    const float* k_b   = (const float*)d_in[6];
    const float* v_w   = (const float*)d_in[7];
    const float* v_b   = (const float*)d_in[8];
    const float* p_w   = (const float*)d_in[9];
    const float* p_b   = (const float*)d_in[10];
    float* out = (float*)d_out;

    const size_t MB = 1 << 20;
    char* wsb = (char*)d_ws;
    unsigned short* ht  = (unsigned short*)(wsb);              // 8 MB  [8192][512]
    unsigned short* wqb = (unsigned short*)(wsb + 8 * MB);     // 4 x 512KB contiguous (q,k,v,p)
    unsigned short* wpb = (unsigned short*)(wsb + 9 * MB + 512 * 1024);
    float*          stats = (float*)(wsb + 10 * MB);           // 1 KB
    unsigned short* qt  = (unsigned short*)(wsb + 11 * MB);    // 8 MB [bh][n][d]
    unsigned short* kt  = (unsigned short*)(wsb + 19 * MB);    // 8 MB
    unsigned short* vt  = (unsigned short*)(wsb + 27 * MB);    // 8 MB [b][c][n]
    unsigned short* at  = (unsigned short*)(wsb + 35 * MB);    // 8 MB [b][n][c]

    gn_stats<<<B_DIM * NGRP, 256, 0, stream>>>(x, stats);
    gn_apply_t<<<dim3(N_DIM / 64, C_DIM / 64, B_DIM), 256, 0, stream>>>(x, stats, gam, bet, ht);

    cast4_bf16<<<dim3(128, 4), 256, 0, stream>>>(q_w, k_w, v_w, p_w, wqb);

    const float escale = 0.044194173824159216f * 1.4426950408889634f;  // scale*log2(e)
    conv_qkv<<<dim3(B_DIM * N_DIM / 64, C_DIM / 64), 256, 0, stream>>>(
        wqb, q_b, k_b, v_b, ht, qt, kt, vt, escale);

    attn_kernel<<<dim3(N_DIM / 128, B_DIM * NHEAD), 512, 0, stream>>>(qt, kt, vt, at);

    conv_proj<<<dim3(B_DIM * N_DIM / 128, C_DIM / 64), 256, 0, stream>>>(wpb, p_b, at, x, out);
}

// Round 11
// 115.905 us; speedup vs baseline: 2.4216x; 1.0052x over previous
//
#include <hip/hip_runtime.h>
#include <hip/hip_bf16.h>
#include <math.h>

#define C_DIM 512
#define N_DIM 2048
#define B_DIM 4
#define NGRP 32
#define GCH 16          // channels per group
#define NHEAD 8
#define HDIM 64
#define EPSV 1e-6f

using f32x4  = __attribute__((ext_vector_type(4))) float;
using bf16x8 = __attribute__((ext_vector_type(8))) short;   // 8 bf16 raw bits (4 VGPRs)

// async global->LDS, 16B per lane; LDS dest = wave-uniform base + lane*16
#define GLL16(gp, lp) __builtin_amdgcn_global_load_lds( \
    (const __attribute__((address_space(1))) unsigned int*)(gp), \
    (__attribute__((address_space(3))) unsigned int*)(lp), 16, 0, 0)

// pack high-16 (truncated bf16) of two f32s: lo16 = a, hi16 = b
#define BFPACK(a, b) __builtin_amdgcn_perm(__float_as_uint(b), __float_as_uint(a), 0x07060302u)

static __device__ __forceinline__ unsigned short f2bf(float f) {
    union { __hip_bfloat16 h; unsigned short u; } cv;
    cv.h = __float2bfloat16(f);
    return cv.u;
}

// ---------------------------------------------------------------------------
// gn_stats: 2 blocks per (b,group) half-slab; partial sums.
// partial[blk*2] = sum, partial[blk*2+1] = sumsq   (blk = bg*2 + half)
// ---------------------------------------------------------------------------
__global__ __launch_bounds__(256) void gn_stats(const float* __restrict__ x,
                                                float* __restrict__ partial) {
    const int HSZ = GCH * N_DIM / 2;        // 16384 floats per half
    int blk = blockIdx.x;                   // 0..255
    const float4* x4 = (const float4*)(x + (size_t)blk * HSZ);
    int tid = threadIdx.x;

    float s = 0.f, ss = 0.f;
    #pragma unroll
    for (int it = 0; it < HSZ / 4 / 256; ++it) {
        float4 v = x4[tid + it * 256];
        s  += v.x + v.y + v.z + v.w;
        ss += v.x * v.x + v.y * v.y + v.z * v.z + v.w * v.w;
    }
    __shared__ float rs[256], rss[256];
    rs[tid] = s; rss[tid] = ss;
    __syncthreads();
    for (int off = 128; off > 0; off >>= 1) {
        if (tid < off) { rs[tid] += rs[tid + off]; rss[tid] += rss[tid + off]; }
        __syncthreads();
    }
    if (tid == 0) {
        partial[blk * 2]     = rs[0];
        partial[blk * 2 + 1] = rss[0];
    }
}

// ---------------------------------------------------------------------------
// gn_apply_t: x [b][c][n] fp32 -> ht [(b*n)][c] bf16 (normalized, transposed).
// Combines the two half-slab partials inline.
// ---------------------------------------------------------------------------
__global__ __launch_bounds__(256) void gn_apply_t(const float* __restrict__ x,
                                                  const float* __restrict__ partial,
                                                  const float* __restrict__ gamma,
                                                  const float* __restrict__ beta,
                                                  unsigned short* __restrict__ ht) {
    __shared__ char smem[8192];     // [64 n][64 c] bf16, rows 128B, XOR-swizzled
    const float GSZI = 1.f / (GCH * N_DIM);
    int n0 = blockIdx.x * 64, c0 = blockIdx.y * 64, b = blockIdx.z;
    int tid = threadIdx.x;
    #pragma unroll
    for (int it = 0; it < 4; ++it) {
        int idx = tid + it * 256;
        int ci = idx >> 4, n4 = (idx & 15) << 2;
        int cg = c0 + ci, grp = cg >> 4;
        int bg = b * NGRP + grp;
        float s  = partial[bg * 4]     + partial[bg * 4 + 2];
        float ss = partial[bg * 4 + 1] + partial[bg * 4 + 3];
        float mean = s * GSZI;
        float var  = ss * GSZI - mean * mean;
        float rstd = rsqrtf(var + EPSV);
        float ga = gamma[cg] * rstd, be = beta[cg] - mean * ga;
        float4 v = *(const float4*)&x[((size_t)b * C_DIM + cg) * N_DIM + n0 + n4];
        float vals[4] = {v.x, v.y, v.z, v.w};
        #pragma unroll
        for (int j = 0; j < 4; ++j) {
            int nl = n4 + j;
            *(unsigned short*)(smem + nl * 128 + ((ci * 2) ^ ((nl & 7) << 4))) =
                f2bf(vals[j] * ga + be);
        }
    }
    __syncthreads();
    #pragma unroll
    for (int i = 0; i < 2; ++i) {
        int idx = tid + i * 256;       // 512 chunks = 64 rows x 8x16B
        int row = idx >> 3, ch = idx & 7;
        bf16x8 v = *(const bf16x8*)(smem + row * 128 + ((ch * 16) ^ ((row & 7) << 4)));
        *(bf16x8*)&ht[((size_t)(b * N_DIM + n0 + row)) * C_DIM + c0 + ch * 8] = v;
    }
}

// ---------------------------------------------------------------------------
// cast4: fp32 -> bf16 for the four 512x512 weights in one launch.
// ---------------------------------------------------------------------------
__global__ __launch_bounds__(256) void cast4_bf16(const float* __restrict__ s0,
                                                  const float* __restrict__ s1,
                                                  const float* __restrict__ s2,
                                                  const float* __restrict__ s3,
                                                  unsigned short* __restrict__ dst) {
    int which = blockIdx.y;
    const float* src = (which == 0) ? s0 : (which == 1) ? s1 : (which == 2) ? s2 : s3;
    size_t idx = (size_t)blockIdx.x * 256 + threadIdx.x;
    const float4* s4 = (const float4*)src;
    float4 a = s4[idx * 2], b = s4[idx * 2 + 1];
    bf16x8 o;
    o[0] = (short)f2bf(a.x); o[1] = (short)f2bf(a.y);
    o[2] = (short)f2bf(a.z); o[3] = (short)f2bf(a.w);
    o[4] = (short)f2bf(b.x); o[5] = (short)f2bf(b.y);
    o[6] = (short)f2bf(b.z); o[7] = (short)f2bf(b.w);
    *(bf16x8*)&dst[(size_t)which * 262144 + idx * 8] = o;
}

// ---------------------------------------------------------------------------
// conv_qkv v2: fused Q/K/V convs. BM=64(o) x BN=128(bn) x BK=64; 512 thr,
// 8 waves (wr=o-half, wc=n-quarter; wave tile 32x32 per weight).
// Staging: waves 0-3 -> Bs (ht), waves 4-7 -> 3 weight tiles.
// Q -> qt [bh][n][d] *escale; K -> kt; V -> vt [b][c][n].
// grid (B*N/128 = 64, C/64 = 8).
// ---------------------------------------------------------------------------
__global__ __launch_bounds__(512) void conv_qkv(const unsigned short* __restrict__ Wall,
                                                const float* __restrict__ q_b,
                                                const float* __restrict__ k_b,
                                                const float* __restrict__ v_b,
                                                const unsigned short* __restrict__ ht,
                                                unsigned short* __restrict__ qt,
                                                unsigned short* __restrict__ kt,
                                                unsigned short* __restrict__ vt,
                                                float escale) {
    __shared__ char smem[40960];     // Bs 16KB | As_q 8KB | As_k 8KB | As_v 8KB

    int bn0 = blockIdx.x * 128;      // flattened b*N + n
    int bo  = blockIdx.y * 64;
    int tid = threadIdx.x;
    int L = tid & 63, w = tid >> 6;
    int g = L >> 4, c = L & 15;
    int wr = w >> 2, wc = w & 3;

    f32x4 acc[3][2][2];
    #pragma unroll
    for (int w3 = 0; w3 < 3; ++w3)
        #pragma unroll
        for (int t = 0; t < 2; ++t)
            #pragma unroll
            for (int u = 0; u < 2; ++u) acc[w3][t][u] = f32x4{0.f, 0.f, 0.f, 0.f};

    for (int k0 = 0; k0 < C_DIM; k0 += 64) {
        if (w < 4) {
            // Bs: 16 x 1KB chunks (128 rows)
            #pragma unroll
            for (int i = 0; i < 4; ++i) {
                int j = w * 4 + i;
                int row = j * 8 + (L >> 3);
                int sl = (L & 7) ^ (row & 7);
                GLL16(ht + (size_t)(bn0 + row) * C_DIM + k0 + sl * 8, smem + j * 1024);
            }
        } else {
            // As: 24 x 1KB chunks (3 weights x 64 rows)
            #pragma unroll
            for (int i = 0; i < 6; ++i) {
                int j = (w - 4) * 6 + i;
                int w3 = j >> 3, jj = j & 7;
                int row = jj * 8 + (L >> 3);
                int sl = (L & 7) ^ (row & 7);
                GLL16(Wall + (size_t)w3 * 262144 + (size_t)(bo + row) * C_DIM + k0 + sl * 8,
                      smem + 16384 + j * 1024);
            }
        }
        __syncthreads();

        bf16x8 bfr[2][2];
        #pragma unroll
        for (int u = 0; u < 2; ++u) {
            int row = wc * 32 + u * 16 + c;
            #pragma unroll
            for (int ks = 0; ks < 2; ++ks)
                bfr[u][ks] = *(const bf16x8*)(smem + row * 128 +
                                              ((g * 16 + ks * 64) ^ ((row & 7) << 4)));
        }
        #pragma unroll
        for (int w3 = 0; w3 < 3; ++w3) {
            char* As = smem + 16384 + w3 * 8192;
            bf16x8 af[2][2];
            #pragma unroll
            for (int t = 0; t < 2; ++t) {
                int row = wr * 32 + t * 16 + c;
                #pragma unroll
                for (int ks = 0; ks < 2; ++ks)
                    af[t][ks] = *(const bf16x8*)(As + row * 128 +
                                                 ((g * 16 + ks * 64) ^ ((row & 7) << 4)));
            }
            #pragma unroll
            for (int ks = 0; ks < 2; ++ks)
                #pragma unroll
                for (int t = 0; t < 2; ++t)
                    #pragma unroll
                    for (int u = 0; u < 2; ++u)
                        acc[w3][t][u] = __builtin_amdgcn_mfma_f32_16x16x32_bf16(
                            af[t][ks], bfr[u][ks], acc[w3][t][u], 0, 0, 0);
        }
        __syncthreads();
    }

    int b  = bn0 >> 11;              // N_DIM = 2048
    int nb = bn0 & (N_DIM - 1);
    int hh = bo >> 6;
    int bh = b * NHEAD + hh;

    // ---- V epilogue: natural [b][c][n] bf16 ----
    #pragma unroll
    for (int t = 0; t < 2; ++t)
        #pragma unroll
        for (int r = 0; r < 4; ++r) {
            int m = bo + wr * 32 + t * 16 + g * 4 + r;
            float bi = v_b[m];
            #pragma unroll
            for (int u = 0; u < 2; ++u) {
                int n = nb + wc * 32 + u * 16 + c;
                vt[((size_t)b * C_DIM + m) * N_DIM + n] = f2bf(acc[2][t][u][r] + bi);
            }
        }

    // ---- Q then K epilogues: transpose through Ts (reuse Bs region, 16KB) ----
    char* Ts = smem;                 // [128 n][64 d] swz
    #pragma unroll
    for (int pass = 0; pass < 2; ++pass) {
        const float* bias = pass ? k_b : q_b;
        float esc = pass ? 1.0f : escale;
        unsigned short* dst = pass ? kt : qt;
        __syncthreads();
        #pragma unroll
        for (int t = 0; t < 2; ++t)
            #pragma unroll
            for (int r = 0; r < 4; ++r) {
                int ml = wr * 32 + t * 16 + g * 4 + r;   // d
                float bi = bias[bo + ml];
                #pragma unroll
                for (int u = 0; u < 2; ++u) {
                    int nl = wc * 32 + u * 16 + c;       // 0..127
                    *(unsigned short*)(Ts + nl * 128 + ((ml * 2) ^ ((nl & 7) << 4))) =
                        f2bf((acc[pass][t][u][r] + bi) * esc);
                }
            }
        __syncthreads();
        #pragma unroll
        for (int i = 0; i < 2; ++i) {
            int idx = tid + i * 512;     // 1024 chunks = 128 rows x 8x16B
            int row = idx >> 3, ch = idx & 7;
            bf16x8 v = *(const bf16x8*)(Ts + row * 128 + ((ch * 16) ^ ((row & 7) << 4)));
            *(bf16x8*)&dst[((size_t)bh * N_DIM + nb + row) * HDIM + ch * 8] = v;
        }
    }
}

// ---------------------------------------------------------------------------
// conv_proj: out fp32 [b][c][n] + residual. (Unchanged.)
// ---------------------------------------------------------------------------
__global__ __launch_bounds__(256) void conv_proj(const unsigned short* __restrict__ Wb,
                                                 const float* __restrict__ bias,
                                                 const unsigned short* __restrict__ Bsrc,
                                                 const float* __restrict__ res,
                                                 float* __restrict__ outf) {
    __shared__ char smem[24576];
    int bn0 = blockIdx.x * 128;
    int bo  = blockIdx.y * 64;
    int tid = threadIdx.x;
    int L = tid & 63, w = tid >> 6;
    int g = L >> 4, c = L & 15;
    int wr = w >> 1, wc = w & 1;

    f32x4 acc[2][4];
    #pragma unroll
    for (int t = 0; t < 2; ++t)
        #pragma unroll
        for (int u = 0; u < 4; ++u) acc[t][u] = f32x4{0.f, 0.f, 0.f, 0.f};

    for (int k0 = 0; k0 < C_DIM; k0 += 64) {
        #pragma unroll
        for (int i = 0; i < 2; ++i) {
            int j = w * 2 + i;
            int ra = j * 8 + (L >> 3);
            int sl = (L & 7) ^ (ra & 7);
            GLL16(Wb + (size_t)(bo + ra) * C_DIM + k0 + sl * 8, smem + j * 1024);
        }
        #pragma unroll
        for (int i = 0; i < 4; ++i) {
            int j = w * 4 + i;
            int rb = j * 8 + (L >> 3);
            int sl = (L & 7) ^ (rb & 7);
            GLL16(Bsrc + (size_t)(bn0 + rb) * C_DIM + k0 + sl * 8, smem + 8192 + j * 1024);
        }
        __syncthreads();

        bf16x8 af[2][2], bfr[4][2];
        #pragma unroll
        for (int t = 0; t < 2; ++t) {
            int row = wr * 32 + t * 16 + c;
            #pragma unroll
            for (int ks = 0; ks < 2; ++ks)
                af[t][ks] = *(const bf16x8*)(smem + row * 128 +
                                             ((g * 16 + ks * 64) ^ ((row & 7) << 4)));
        }
        #pragma unroll
        for (int u = 0; u < 4; ++u) {
            int row = wc * 64 + u * 16 + c;
            #pragma unroll
            for (int ks = 0; ks < 2; ++ks)
                bfr[u][ks] = *(const bf16x8*)(smem + 8192 + row * 128 +
                                              ((g * 16 + ks * 64) ^ ((row & 7) << 4)));
        }
        #pragma unroll
        for (int ks = 0; ks < 2; ++ks)
            #pragma unroll
            for (int t = 0; t < 2; ++t)
                #pragma unroll
                for (int u = 0; u < 4; ++u)
                    acc[t][u] = __builtin_amdgcn_mfma_f32_16x16x32_bf16(
                        af[t][ks], bfr[u][ks], acc[t][u], 0, 0, 0);
        __syncthreads();
    }

    int b  = bn0 >> 11;
    int nb = bn0 & (N_DIM - 1);
    #pragma unroll
    for (int t = 0; t < 2; ++t)
        #pragma unroll
        for (int r = 0; r < 4; ++r) {
            int m = bo + wr * 32 + t * 16 + g * 4 + r;
            float bi = bias[m];
            #pragma unroll
            for (int u = 0; u < 4; ++u) {
                int n = nb + wc * 64 + u * 16 + c;
                size_t off = ((size_t)b * C_DIM + m) * N_DIM + n;
                outf[off] = acc[t][u][r] + bi + res[off];
            }
        }
}

// ---------------------------------------------------------------------------
// MFMA bf16 flash attention, swapped-operand form. 8 waves, QBLK=128.
// R11: f32x4-vectorized softmax arithmetic (packed-math friendly).
// ---------------------------------------------------------------------------
__global__ __launch_bounds__(512, 4) void attn_kernel(const unsigned short* __restrict__ Qt,
                                                      const unsigned short* __restrict__ Kt,
                                                      const unsigned short* __restrict__ Vt,
                                                      unsigned short* __restrict__ at) {
    __shared__ char smem[49152];
    // [0,16K): Q staging -> P/O strips; [16K,32K): buf0 (K|V); [32K,48K): buf1

    int q0 = blockIdx.x * 128;
    int bh = blockIdx.y;
    int b = bh >> 3, hh = bh & 7;
    int tid = threadIdx.x;
    int L = tid & 63, w = tid >> 6;        // 8 waves
    int g = L >> 4, c = L & 15;

    const unsigned short* Qh = Qt + (size_t)bh * N_DIM * HDIM;
    const unsigned short* Kh = Kt + (size_t)bh * N_DIM * HDIM;
    const unsigned short* Vh = Vt + (size_t)bh * HDIM * N_DIM;

    // ---- prologue: stage Q (16 x 1KB) + K/V tile 0 into buf0, all async ----
    #pragma unroll
    for (int i = 0; i < 2; ++i) {
        int j = w * 2 + i;
        int row = j * 8 + (L >> 3);        // 0..127
        int sl = (L & 7) ^ (row & 7);
        GLL16(Qh + (size_t)(q0 + row) * HDIM + sl * 8, smem + j * 1024);
    }
    int srow = w * 8 + (L >> 3);           // staging row 0..63
    int ssl  = (L & 7) ^ (srow & 7);
    GLL16(Kh + (size_t)srow * HDIM + ssl * 8, smem + 16384 + w * 1024);
    GLL16(Vh + (size_t)srow * N_DIM + ssl * 8, smem + 24576 + w * 1024);
    __syncthreads();                       // drains vmcnt -> Q + tile0 ready

    // ---- hoisted addresses ----
    int csw = (c & 7) << 4;
    char* kb0 = smem + 16384 + c * 128 + ((g * 16) ^ csw);        // K frag ks=0
    char* kb1 = smem + 16384 + c * 128 + ((g * 16 + 64) ^ csw);   // K frag ks=1
    char* pb  = smem + (w * 16 + c) * 128;                        // wave-private strip
    char* pw0 = pb + ((g * 8) ^ csw);
    char* pw1 = pb + ((32 + g * 8) ^ csw);
    char* pw2 = pb + ((64 + g * 8) ^ csw);
    char* pw3 = pb + ((96 + g * 8) ^ csw);
    char* pr0 = pb + ((g * 16) ^ csw);
    char* pr1 = pb + ((64 + g * 16) ^ csw);

    // Q fragments from strip region (same addresses as pr0/pr1)
    bf16x8 qf[2];
    qf[0] = *(const bf16x8*)pr0;
    qf[1] = *(const bf16x8*)pr1;

    // staging global pointers -> tile 1
    const unsigned short* kgp = Kh + (size_t)(64 + srow) * HDIM + ssl * 8;
    const unsigned short* vgp = Vh + (size_t)srow * N_DIM + 64 + ssl * 8;

    f32x4 oacc[4];
    #pragma unroll
    for (int t = 0; t < 4; ++t) oacc[t] = f32x4{0.f, 0.f, 0.f, 0.f};
    float m_r = -INFINITY, l_part = 0.f;

    auto tile = [&](int BOFF) {
        // ---- S^T = K Q^T : D[kpos=16t+4g+r][q=16w+c] ----
        f32x4 sacc[4];
        #pragma unroll
        for (int t = 0; t < 4; ++t) sacc[t] = f32x4{0.f, 0.f, 0.f, 0.f};
        __builtin_amdgcn_s_setprio(1);
        #pragma unroll
        for (int t = 0; t < 4; ++t) {
            bf16x8 kf0 = *(const bf16x8*)(kb0 + BOFF + t * 2048);
            bf16x8 kf1 = *(const bf16x8*)(kb1 + BOFF + t * 2048);
            sacc[t] = __builtin_amdgcn_mfma_f32_16x16x32_bf16(kf0, qf[0], sacc[t], 0, 0, 0);
            sacc[t] = __builtin_amdgcn_mfma_f32_16x16x32_bf16(kf1, qf[1], sacc[t], 0, 0, 0);
        }
        __builtin_amdgcn_s_setprio(0);

        // ---- softmax over kpos (exp2 domain); zero-shfl steady state ----
        float t0 = fmaxf(fmaxf(sacc[0][0], sacc[0][1]), sacc[0][2]);
        float t1 = fmaxf(fmaxf(sacc[0][3], sacc[1][0]), sacc[1][1]);
        float t2 = fmaxf(fmaxf(sacc[1][2], sacc[1][3]), sacc[2][0]);
        float t3 = fmaxf(fmaxf(sacc[2][1], sacc[2][2]), sacc[2][3]);
        float t4 = fmaxf(fmaxf(sacc[3][0], sacc[3][1]), sacc[3][2]);
        float mloc = fmaxf(fmaxf(fmaxf(t0, t1), fmaxf(t2, t3)), fmaxf(t4, sacc[3][3]));
        if (!__all(mloc - m_r <= 6.0f)) {       // rare: row max grew
            mloc = fmaxf(mloc, __shfl_xor(mloc, 16));
            mloc = fmaxf(mloc, __shfl_xor(mloc, 32));
            float mn = fmaxf(m_r, mloc);
            float fac = exp2f(m_r - mn);
            m_r = mn;
            l_part *= fac;
            #pragma unroll
            for (int t = 0; t < 4; ++t) oacc[t] = oacc[t] * fac;
        }
        f32x4 m4 = {m_r, m_r, m_r, m_r};
        f32x4 p[4];
        #pragma unroll
        for (int t = 0; t < 4; ++t) {
            f32x4 d = sacc[t] - m4;            // packed-math candidate
            p[t][0] = exp2f(d[0]);
            p[t][1] = exp2f(d[1]);
            p[t][2] = exp2f(d[2]);
            p[t][3] = exp2f(d[3]);
        }
        f32x4 racc = (p[0] + p[1]) + (p[2] + p[3]);
        l_part += (racc[0] + racc[1]) + (racc[2] + racc[3]);

        unsigned pk[4][2];
        #pragma unroll
        for (int t = 0; t < 4; ++t) {
            pk[t][0] = BFPACK(p[t][0], p[t][1]);
            pk[t][1] = BFPACK(p[t][2], p[t][3]);
        }

        // ---- P^T strip (wave-private) ----
        *(unsigned long long*)pw0 = (unsigned long long)pk[0][0] | ((unsigned long long)pk[0][1] << 32);
        *(unsigned long long*)pw1 = (unsigned long long)pk[1][0] | ((unsigned long long)pk[1][1] << 32);
        *(unsigned long long*)pw2 = (unsigned long long)pk[2][0] | ((unsigned long long)pk[2][1] << 32);
        *(unsigned long long*)pw3 = (unsigned long long)pk[3][0] | ((unsigned long long)pk[3][1] << 32);

        // ---- O^T += V^T P^T ----
        __builtin_amdgcn_s_setprio(1);
        {
            bf16x8 pf0 = *(const bf16x8*)pr0;
            #pragma unroll
            for (int t = 0; t < 4; ++t) {
                bf16x8 vf = *(const bf16x8*)(kb0 + BOFF + 8192 + t * 2048);
                oacc[t] = __builtin_amdgcn_mfma_f32_16x16x32_bf16(vf, pf0, oacc[t], 0, 0, 0);
            }
            bf16x8 pf1 = *(const bf16x8*)pr1;
            #pragma unroll
            for (int t = 0; t < 4; ++t) {
                bf16x8 vf = *(const bf16x8*)(kb1 + BOFF + 8192 + t * 2048);
                oacc[t] = __builtin_amdgcn_mfma_f32_16x16x32_bf16(vf, pf1, oacc[t], 0, 0, 0);
            }
        }
        __builtin_amdgcn_s_setprio(0);
    };

    for (int i = 0; i < 16; ++i) {
        // body A: stage tile(2i+1) -> buf1, compute buf0
        GLL16(kgp, smem + 32768 + w * 1024);
        GLL16(vgp, smem + 40960 + w * 1024);
        kgp += 64 * HDIM;
        vgp += 64;
        tile(0);
        __syncthreads();
        // body B: stage tile(2i+2) -> buf0 (guarded), compute buf1
        if (i < 15) {
            GLL16(kgp, smem + 16384 + w * 1024);
            GLL16(vgp, smem + 24576 + w * 1024);
            kgp += 64 * HDIM;
            vgp += 64;
        }
        tile(16384);
        __syncthreads();
    }

    // ---- deferred l reduction + epilogue ----
    float l_r = l_part;
    l_r += __shfl_xor(l_r, 16);
    l_r += __shfl_xor(l_r, 32);
    float oinv = 1.f / l_r;
    {
        unsigned lo, hi;
        lo = BFPACK(oacc[0][0] * oinv, oacc[0][1] * oinv);
        hi = BFPACK(oacc[0][2] * oinv, oacc[0][3] * oinv);
        *(unsigned long long*)pw0 = (unsigned long long)lo | ((unsigned long long)hi << 32);
        lo = BFPACK(oacc[1][0] * oinv, oacc[1][1] * oinv);
        hi = BFPACK(oacc[1][2] * oinv, oacc[1][3] * oinv);
        *(unsigned long long*)pw1 = (unsigned long long)lo | ((unsigned long long)hi << 32);
        lo = BFPACK(oacc[2][0] * oinv, oacc[2][1] * oinv);
        hi = BFPACK(oacc[2][2] * oinv, oacc[2][3] * oinv);
        *(unsigned long long*)pw2 = (unsigned long long)lo | ((unsigned long long)hi << 32);
        lo = BFPACK(oacc[3][0] * oinv, oacc[3][1] * oinv);
        hi = BFPACK(oacc[3][2] * oinv, oacc[3][3] * oinv);
        *(unsigned long long*)pw3 = (unsigned long long)lo | ((unsigned long long)hi << 32);
    }
    char* wbase = smem + w * 2048;         // wave's 16 rows
    #pragma unroll
    for (int i = 0; i < 2; ++i) {
        int idx = L + i * 64;              // 128 chunks = 16 rows x 8x16B
        int row = idx >> 3, ch = idx & 7;
        bf16x8 v = *(const bf16x8*)(wbase + row * 128 + ((ch * 16) ^ ((row & 7) << 4)));
        *(bf16x8*)&at[((size_t)(b * N_DIM + q0 + w * 16 + row)) * C_DIM + hh * HDIM + ch * 8] = v;
    }
}

// ---------------------------------------------------------------------------
extern "C" void kernel_launch(void* const* d_in, const int* in_sizes, int n_in,
                              void* d_out, int out_size, void* d_ws, size_t ws_size,
                              hipStream_t stream) {
    (void)in_sizes; (void)n_in; (void)out_size; (void)ws_size;
    const float* x     = (const float*)d_in[0];
    const float* gam   = (const float*)d_in[1];
    const float* bet   = (const float*)d_in[2];
    const float* q_w   = (const float*)d_in[3];
    const float* q_b   = (const float*)d_in[4];
    const float* k_w   = (const float*)d_in[5];
    const float* k_b   = (const float*)d_in[6];
    const float* v_w   = (const float*)d_in[7];
    const float* v_b   = (const float*)d_in[8];
    const float* p_w   = (const float*)d_in[9];
    const float* p_b   = (const float*)d_in[10];
    float* out = (float*)d_out;

    const size_t MB = 1 << 20;
    char* wsb = (char*)d_ws;
    unsigned short* ht  = (unsigned short*)(wsb);              // 8 MB  [8192][512]
    unsigned short* wqb = (unsigned short*)(wsb + 8 * MB);     // 4 x 512KB contiguous (q,k,v,p)
    unsigned short* wpb = (unsigned short*)(wsb + 9 * MB + 512 * 1024);
    float*          partial = (float*)(wsb + 10 * MB);         // 2 KB
    unsigned short* qt  = (unsigned short*)(wsb + 11 * MB);    // 8 MB [bh][n][d]
    unsigned short* kt  = (unsigned short*)(wsb + 19 * MB);    // 8 MB
    unsigned short* vt  = (unsigned short*)(wsb + 27 * MB);    // 8 MB [b][c][n]
    unsigned short* at  = (unsigned short*)(wsb + 35 * MB);    // 8 MB [b][n][c]

    gn_stats<<<B_DIM * NGRP * 2, 256, 0, stream>>>(x, partial);
    gn_apply_t<<<dim3(N_DIM / 64, C_DIM / 64, B_DIM), 256, 0, stream>>>(x, partial, gam, bet, ht);

    cast4_bf16<<<dim3(128, 4), 256, 0, stream>>>(q_w, k_w, v_w, p_w, wqb);

    const float escale = 0.044194173824159216f * 1.4426950408889634f;  // scale*log2(e)
    conv_qkv<<<dim3(B_DIM * N_DIM / 128, C_DIM / 64), 512, 0, stream>>>(
        wqb, q_b, k_b, v_b, ht, qt, kt, vt, escale);

    attn_kernel<<<dim3(N_DIM / 128, B_DIM * NHEAD), 512, 0, stream>>>(qt, kt, vt, at);

    conv_proj<<<dim3(B_DIM * N_DIM / 128, C_DIM / 64), 256, 0, stream>>>(wpb, p_b, at, x, out);
}

// Round 12
// 113.537 us; speedup vs baseline: 2.4721x; 1.0209x over previous
//
#include <hip/hip_runtime.h>
#include <hip/hip_bf16.h>
#include <math.h>

#define C_DIM 512
#define N_DIM 2048
#define B_DIM 4
#define NGRP 32
#define GCH 16          // channels per group
#define NHEAD 8
#define HDIM 64
#define EPSV 1e-6f

using f32x4  = __attribute__((ext_vector_type(4))) float;
using bf16x8 = __attribute__((ext_vector_type(8))) short;   // 8 bf16 raw bits (4 VGPRs)

// async global->LDS, 16B per lane; LDS dest = wave-uniform base + lane*16
#define GLL16(gp, lp) __builtin_amdgcn_global_load_lds( \
    (const __attribute__((address_space(1))) unsigned int*)(gp), \
    (__attribute__((address_space(3))) unsigned int*)(lp), 16, 0, 0)

// pack high-16 (truncated bf16) of two f32s: lo16 = a, hi16 = b
#define BFPACK(a, b) __builtin_amdgcn_perm(__float_as_uint(b), __float_as_uint(a), 0x07060302u)

static __device__ __forceinline__ unsigned short f2bf(float f) {
    union { __hip_bfloat16 h; unsigned short u; } cv;
    cv.h = __float2bfloat16(f);
    return cv.u;
}

// ---------------------------------------------------------------------------
// gn_stats: 2 blocks per (b,group) half-slab; partial sums.
// ---------------------------------------------------------------------------
__global__ __launch_bounds__(256) void gn_stats(const float* __restrict__ x,
                                                float* __restrict__ partial) {
    const int HSZ = GCH * N_DIM / 2;        // 16384 floats per half
    int blk = blockIdx.x;                   // 0..255
    const float4* x4 = (const float4*)(x + (size_t)blk * HSZ);
    int tid = threadIdx.x;

    float s = 0.f, ss = 0.f;
    #pragma unroll
    for (int it = 0; it < HSZ / 4 / 256; ++it) {
        float4 v = x4[tid + it * 256];
        s  += v.x + v.y + v.z + v.w;
        ss += v.x * v.x + v.y * v.y + v.z * v.z + v.w * v.w;
    }
    __shared__ float rs[256], rss[256];
    rs[tid] = s; rss[tid] = ss;
    __syncthreads();
    for (int off = 128; off > 0; off >>= 1) {
        if (tid < off) { rs[tid] += rs[tid + off]; rss[tid] += rss[tid + off]; }
        __syncthreads();
    }
    if (tid == 0) {
        partial[blk * 2]     = rs[0];
        partial[blk * 2 + 1] = rss[0];
    }
}

// ---------------------------------------------------------------------------
// gn_apply_t: x [b][c][n] fp32 -> ht [(b*n)][c] bf16 (normalized, transposed).
// ---------------------------------------------------------------------------
__global__ __launch_bounds__(256) void gn_apply_t(const float* __restrict__ x,
                                                  const float* __restrict__ partial,
                                                  const float* __restrict__ gamma,
                                                  const float* __restrict__ beta,
                                                  unsigned short* __restrict__ ht) {
    __shared__ char smem[8192];     // [64 n][64 c] bf16, rows 128B, XOR-swizzled
    const float GSZI = 1.f / (GCH * N_DIM);
    int n0 = blockIdx.x * 64, c0 = blockIdx.y * 64, b = blockIdx.z;
    int tid = threadIdx.x;
    #pragma unroll
    for (int it = 0; it < 4; ++it) {
        int idx = tid + it * 256;
        int ci = idx >> 4, n4 = (idx & 15) << 2;
        int cg = c0 + ci, grp = cg >> 4;
        int bg = b * NGRP + grp;
        float s  = partial[bg * 4]     + partial[bg * 4 + 2];
        float ss = partial[bg * 4 + 1] + partial[bg * 4 + 3];
        float mean = s * GSZI;
        float var  = ss * GSZI - mean * mean;
        float rstd = rsqrtf(var + EPSV);
        float ga = gamma[cg] * rstd, be = beta[cg] - mean * ga;
        float4 v = *(const float4*)&x[((size_t)b * C_DIM + cg) * N_DIM + n0 + n4];
        float vals[4] = {v.x, v.y, v.z, v.w};
        #pragma unroll
        for (int j = 0; j < 4; ++j) {
            int nl = n4 + j;
            *(unsigned short*)(smem + nl * 128 + ((ci * 2) ^ ((nl & 7) << 4))) =
                f2bf(vals[j] * ga + be);
        }
    }
    __syncthreads();
    #pragma unroll
    for (int i = 0; i < 2; ++i) {
        int idx = tid + i * 256;       // 512 chunks = 64 rows x 8x16B
        int row = idx >> 3, ch = idx & 7;
        bf16x8 v = *(const bf16x8*)(smem + row * 128 + ((ch * 16) ^ ((row & 7) << 4)));
        *(bf16x8*)&ht[((size_t)(b * N_DIM + n0 + row)) * C_DIM + c0 + ch * 8] = v;
    }
}

// ---------------------------------------------------------------------------
// cast4: fp32 -> bf16 for the four 512x512 weights in one launch.
// ---------------------------------------------------------------------------
__global__ __launch_bounds__(256) void cast4_bf16(const float* __restrict__ s0,
                                                  const float* __restrict__ s1,
                                                  const float* __restrict__ s2,
                                                  const float* __restrict__ s3,
                                                  unsigned short* __restrict__ dst) {
    int which = blockIdx.y;
    const float* src = (which == 0) ? s0 : (which == 1) ? s1 : (which == 2) ? s2 : s3;
    size_t idx = (size_t)blockIdx.x * 256 + threadIdx.x;
    const float4* s4 = (const float4*)src;
    float4 a = s4[idx * 2], b = s4[idx * 2 + 1];
    bf16x8 o;
    o[0] = (short)f2bf(a.x); o[1] = (short)f2bf(a.y);
    o[2] = (short)f2bf(a.z); o[3] = (short)f2bf(a.w);
    o[4] = (short)f2bf(b.x); o[5] = (short)f2bf(b.y);
    o[6] = (short)f2bf(b.z); o[7] = (short)f2bf(b.w);
    *(bf16x8*)&dst[(size_t)which * 262144 + idx * 8] = o;
}

// ---------------------------------------------------------------------------
// conv_qkv v2: fused Q/K/V convs. (Unchanged from R11.)
// ---------------------------------------------------------------------------
__global__ __launch_bounds__(512) void conv_qkv(const unsigned short* __restrict__ Wall,
                                                const float* __restrict__ q_b,
                                                const float* __restrict__ k_b,
                                                const float* __restrict__ v_b,
                                                const unsigned short* __restrict__ ht,
                                                unsigned short* __restrict__ qt,
                                                unsigned short* __restrict__ kt,
                                                unsigned short* __restrict__ vt,
                                                float escale) {
    __shared__ char smem[40960];     // Bs 16KB | As_q 8KB | As_k 8KB | As_v 8KB

    int bn0 = blockIdx.x * 128;      // flattened b*N + n
    int bo  = blockIdx.y * 64;
    int tid = threadIdx.x;
    int L = tid & 63, w = tid >> 6;
    int g = L >> 4, c = L & 15;
    int wr = w >> 2, wc = w & 3;

    f32x4 acc[3][2][2];
    #pragma unroll
    for (int w3 = 0; w3 < 3; ++w3)
        #pragma unroll
        for (int t = 0; t < 2; ++t)
            #pragma unroll
            for (int u = 0; u < 2; ++u) acc[w3][t][u] = f32x4{0.f, 0.f, 0.f, 0.f};

    for (int k0 = 0; k0 < C_DIM; k0 += 64) {
        if (w < 4) {
            #pragma unroll
            for (int i = 0; i < 4; ++i) {
                int j = w * 4 + i;
                int row = j * 8 + (L >> 3);
                int sl = (L & 7) ^ (row & 7);
                GLL16(ht + (size_t)(bn0 + row) * C_DIM + k0 + sl * 8, smem + j * 1024);
            }
        } else {
            #pragma unroll
            for (int i = 0; i < 6; ++i) {
                int j = (w - 4) * 6 + i;
                int w3 = j >> 3, jj = j & 7;
                int row = jj * 8 + (L >> 3);
                int sl = (L & 7) ^ (row & 7);
                GLL16(Wall + (size_t)w3 * 262144 + (size_t)(bo + row) * C_DIM + k0 + sl * 8,
                      smem + 16384 + j * 1024);
            }
        }
        __syncthreads();

        bf16x8 bfr[2][2];
        #pragma unroll
        for (int u = 0; u < 2; ++u) {
            int row = wc * 32 + u * 16 + c;
            #pragma unroll
            for (int ks = 0; ks < 2; ++ks)
                bfr[u][ks] = *(const bf16x8*)(smem + row * 128 +
                                              ((g * 16 + ks * 64) ^ ((row & 7) << 4)));
        }
        #pragma unroll
        for (int w3 = 0; w3 < 3; ++w3) {
            char* As = smem + 16384 + w3 * 8192;
            bf16x8 af[2][2];
            #pragma unroll
            for (int t = 0; t < 2; ++t) {
                int row = wr * 32 + t * 16 + c;
                #pragma unroll
                for (int ks = 0; ks < 2; ++ks)
                    af[t][ks] = *(const bf16x8*)(As + row * 128 +
                                                 ((g * 16 + ks * 64) ^ ((row & 7) << 4)));
            }
            #pragma unroll
            for (int ks = 0; ks < 2; ++ks)
                #pragma unroll
                for (int t = 0; t < 2; ++t)
                    #pragma unroll
                    for (int u = 0; u < 2; ++u)
                        acc[w3][t][u] = __builtin_amdgcn_mfma_f32_16x16x32_bf16(
                            af[t][ks], bfr[u][ks], acc[w3][t][u], 0, 0, 0);
        }
        __syncthreads();
    }

    int b  = bn0 >> 11;              // N_DIM = 2048
    int nb = bn0 & (N_DIM - 1);
    int hh = bo >> 6;
    int bh = b * NHEAD + hh;

    #pragma unroll
    for (int t = 0; t < 2; ++t)
        #pragma unroll
        for (int r = 0; r < 4; ++r) {
            int m = bo + wr * 32 + t * 16 + g * 4 + r;
            float bi = v_b[m];
            #pragma unroll
            for (int u = 0; u < 2; ++u) {
                int n = nb + wc * 32 + u * 16 + c;
                vt[((size_t)b * C_DIM + m) * N_DIM + n] = f2bf(acc[2][t][u][r] + bi);
            }
        }

    char* Ts = smem;                 // [128 n][64 d] swz
    #pragma unroll
    for (int pass = 0; pass < 2; ++pass) {
        const float* bias = pass ? k_b : q_b;
        float esc = pass ? 1.0f : escale;
        unsigned short* dst = pass ? kt : qt;
        __syncthreads();
        #pragma unroll
        for (int t = 0; t < 2; ++t)
            #pragma unroll
            for (int r = 0; r < 4; ++r) {
                int ml = wr * 32 + t * 16 + g * 4 + r;   // d
                float bi = bias[bo + ml];
                #pragma unroll
                for (int u = 0; u < 2; ++u) {
                    int nl = wc * 32 + u * 16 + c;       // 0..127
                    *(unsigned short*)(Ts + nl * 128 + ((ml * 2) ^ ((nl & 7) << 4))) =
                        f2bf((acc[pass][t][u][r] + bi) * esc);
                }
            }
        __syncthreads();
        #pragma unroll
        for (int i = 0; i < 2; ++i) {
            int idx = tid + i * 512;     // 1024 chunks = 128 rows x 8x16B
            int row = idx >> 3, ch = idx & 7;
            bf16x8 v = *(const bf16x8*)(Ts + row * 128 + ((ch * 16) ^ ((row & 7) << 4)));
            *(bf16x8*)&dst[((size_t)bh * N_DIM + nb + row) * HDIM + ch * 8] = v;
        }
    }
}

// ---------------------------------------------------------------------------
// conv_proj: out fp32 [b][c][n] + residual. (Unchanged.)
// ---------------------------------------------------------------------------
__global__ __launch_bounds__(256) void conv_proj(const unsigned short* __restrict__ Wb,
                                                 const float* __restrict__ bias,
                                                 const unsigned short* __restrict__ Bsrc,
                                                 const float* __restrict__ res,
                                                 float* __restrict__ outf) {
    __shared__ char smem[24576];
    int bn0 = blockIdx.x * 128;
    int bo  = blockIdx.y * 64;
    int tid = threadIdx.x;
    int L = tid & 63, w = tid >> 6;
    int g = L >> 4, c = L & 15;
    int wr = w >> 1, wc = w & 1;

    f32x4 acc[2][4];
    #pragma unroll
    for (int t = 0; t < 2; ++t)
        #pragma unroll
        for (int u = 0; u < 4; ++u) acc[t][u] = f32x4{0.f, 0.f, 0.f, 0.f};

    for (int k0 = 0; k0 < C_DIM; k0 += 64) {
        #pragma unroll
        for (int i = 0; i < 2; ++i) {
            int j = w * 2 + i;
            int ra = j * 8 + (L >> 3);
            int sl = (L & 7) ^ (ra & 7);
            GLL16(Wb + (size_t)(bo + ra) * C_DIM + k0 + sl * 8, smem + j * 1024);
        }
        #pragma unroll
        for (int i = 0; i < 4; ++i) {
            int j = w * 4 + i;
            int rb = j * 8 + (L >> 3);
            int sl = (L & 7) ^ (rb & 7);
            GLL16(Bsrc + (size_t)(bn0 + rb) * C_DIM + k0 + sl * 8, smem + 8192 + j * 1024);
        }
        __syncthreads();

        bf16x8 af[2][2], bfr[4][2];
        #pragma unroll
        for (int t = 0; t < 2; ++t) {
            int row = wr * 32 + t * 16 + c;
            #pragma unroll
            for (int ks = 0; ks < 2; ++ks)
                af[t][ks] = *(const bf16x8*)(smem + row * 128 +
                                             ((g * 16 + ks * 64) ^ ((row & 7) << 4)));
        }
        #pragma unroll
        for (int u = 0; u < 4; ++u) {
            int row = wc * 64 + u * 16 + c;
            #pragma unroll
            for (int ks = 0; ks < 2; ++ks)
                bfr[u][ks] = *(const bf16x8*)(smem + 8192 + row * 128 +
                                              ((g * 16 + ks * 64) ^ ((row & 7) << 4)));
        }
        #pragma unroll
        for (int ks = 0; ks < 2; ++ks)
            #pragma unroll
            for (int t = 0; t < 2; ++t)
                #pragma unroll
                for (int u = 0; u < 4; ++u)
                    acc[t][u] = __builtin_amdgcn_mfma_f32_16x16x32_bf16(
                        af[t][ks], bfr[u][ks], acc[t][u], 0, 0, 0);
        __syncthreads();
    }

    int b  = bn0 >> 11;
    int nb = bn0 & (N_DIM - 1);
    #pragma unroll
    for (int t = 0; t < 2; ++t)
        #pragma unroll
        for (int r = 0; r < 4; ++r) {
            int m = bo + wr * 32 + t * 16 + g * 4 + r;
            float bi = bias[m];
            #pragma unroll
            for (int u = 0; u < 4; ++u) {
                int n = nb + wc * 64 + u * 16 + c;
                size_t off = ((size_t)b * C_DIM + m) * N_DIM + n;
                outf[off] = acc[t][u][r] + bi + res[off];
            }
        }
}

// ---------------------------------------------------------------------------
// MFMA bf16 flash attention, swapped-operand form. 8 waves, QBLK=128.
// R12: XCD-aware work remap — XCD k handles heads {k,k+8,k+16,k+24}, so each
// XCD's L2 caches only 4 heads' K/V (2MB), eliminating 8x cross-XCD re-fetch.
// ---------------------------------------------------------------------------
__global__ __launch_bounds__(512, 4) void attn_kernel(const unsigned short* __restrict__ Qt,
                                                      const unsigned short* __restrict__ Kt,
                                                      const unsigned short* __restrict__ Vt,
                                                      unsigned short* __restrict__ at) {
    __shared__ char smem[49152];
    // [0,16K): Q staging -> P/O strips; [16K,32K): buf0 (K|V); [32K,48K): buf1

    // ---- XCD-aware remap (grid = 512 linear blocks, XCD = d % 8) ----
    int d = blockIdx.x;                // 0..511 dispatch id
    int xcd = d & 7;
    int slot = d >> 3;                 // 0..63 within XCD
    int bh = xcd + 8 * (slot >> 4);    // heads {xcd, xcd+8, xcd+16, xcd+24}
    int q0 = (slot & 15) * 128;

    int b = bh >> 3, hh = bh & 7;
    int tid = threadIdx.x;
    int L = tid & 63, w = tid >> 6;        // 8 waves
    int g = L >> 4, c = L & 15;

    const unsigned short* Qh = Qt + (size_t)bh * N_DIM * HDIM;
    const unsigned short* Kh = Kt + (size_t)bh * N_DIM * HDIM;
    const unsigned short* Vh = Vt + (size_t)bh * HDIM * N_DIM;

    // ---- prologue: stage Q (16 x 1KB) + K/V tile 0 into buf0, all async ----
    #pragma unroll
    for (int i = 0; i < 2; ++i) {
        int j = w * 2 + i;
        int row = j * 8 + (L >> 3);        // 0..127
        int sl = (L & 7) ^ (row & 7);
        GLL16(Qh + (size_t)(q0 + row) * HDIM + sl * 8, smem + j * 1024);
    }
    int srow = w * 8 + (L >> 3);           // staging row 0..63
    int ssl  = (L & 7) ^ (srow & 7);
    GLL16(Kh + (size_t)srow * HDIM + ssl * 8, smem + 16384 + w * 1024);
    GLL16(Vh + (size_t)srow * N_DIM + ssl * 8, smem + 24576 + w * 1024);
    __syncthreads();                       // drains vmcnt -> Q + tile0 ready

    // ---- hoisted addresses ----
    int csw = (c & 7) << 4;
    char* kb0 = smem + 16384 + c * 128 + ((g * 16) ^ csw);        // K frag ks=0
    char* kb1 = smem + 16384 + c * 128 + ((g * 16 + 64) ^ csw);   // K frag ks=1
    char* pb  = smem + (w * 16 + c) * 128;                        // wave-private strip
    char* pw0 = pb + ((g * 8) ^ csw);
    char* pw1 = pb + ((32 + g * 8) ^ csw);
    char* pw2 = pb + ((64 + g * 8) ^ csw);
    char* pw3 = pb + ((96 + g * 8) ^ csw);
    char* pr0 = pb + ((g * 16) ^ csw);
    char* pr1 = pb + ((64 + g * 16) ^ csw);

    // Q fragments from strip region (same addresses as pr0/pr1)
    bf16x8 qf[2];
    qf[0] = *(const bf16x8*)pr0;
    qf[1] = *(const bf16x8*)pr1;

    // staging global pointers -> tile 1
    const unsigned short* kgp = Kh + (size_t)(64 + srow) * HDIM + ssl * 8;
    const unsigned short* vgp = Vh + (size_t)srow * N_DIM + 64 + ssl * 8;

    f32x4 oacc[4];
    #pragma unroll
    for (int t = 0; t < 4; ++t) oacc[t] = f32x4{0.f, 0.f, 0.f, 0.f};
    float m_r = -INFINITY, l_part = 0.f;

    auto tile = [&](int BOFF) {
        // ---- S^T = K Q^T : D[kpos=16t+4g+r][q=16w+c] ----
        f32x4 sacc[4];
        #pragma unroll
        for (int t = 0; t < 4; ++t) sacc[t] = f32x4{0.f, 0.f, 0.f, 0.f};
        __builtin_amdgcn_s_setprio(1);
        #pragma unroll
        for (int t = 0; t < 4; ++t) {
            bf16x8 kf0 = *(const bf16x8*)(kb0 + BOFF + t * 2048);
            bf16x8 kf1 = *(const bf16x8*)(kb1 + BOFF + t * 2048);
            sacc[t] = __builtin_amdgcn_mfma_f32_16x16x32_bf16(kf0, qf[0], sacc[t], 0, 0, 0);
            sacc[t] = __builtin_amdgcn_mfma_f32_16x16x32_bf16(kf1, qf[1], sacc[t], 0, 0, 0);
        }
        __builtin_amdgcn_s_setprio(0);

        // ---- softmax over kpos (exp2 domain); zero-shfl steady state ----
        float t0 = fmaxf(fmaxf(sacc[0][0], sacc[0][1]), sacc[0][2]);
        float t1 = fmaxf(fmaxf(sacc[0][3], sacc[1][0]), sacc[1][1]);
        float t2 = fmaxf(fmaxf(sacc[1][2], sacc[1][3]), sacc[2][0]);
        float t3 = fmaxf(fmaxf(sacc[2][1], sacc[2][2]), sacc[2][3]);
        float t4 = fmaxf(fmaxf(sacc[3][0], sacc[3][1]), sacc[3][2]);
        float mloc = fmaxf(fmaxf(fmaxf(t0, t1), fmaxf(t2, t3)), fmaxf(t4, sacc[3][3]));
        if (!__all(mloc - m_r <= 6.0f)) {       // rare: row max grew
            mloc = fmaxf(mloc, __shfl_xor(mloc, 16));
            mloc = fmaxf(mloc, __shfl_xor(mloc, 32));
            float mn = fmaxf(m_r, mloc);
            float fac = exp2f(m_r - mn);
            m_r = mn;
            l_part *= fac;
            #pragma unroll
            for (int t = 0; t < 4; ++t) oacc[t] = oacc[t] * fac;
        }
        f32x4 m4 = {m_r, m_r, m_r, m_r};
        f32x4 p[4];
        #pragma unroll
        for (int t = 0; t < 4; ++t) {
            f32x4 dd = sacc[t] - m4;
            p[t][0] = exp2f(dd[0]);
            p[t][1] = exp2f(dd[1]);
            p[t][2] = exp2f(dd[2]);
            p[t][3] = exp2f(dd[3]);
        }
        f32x4 racc = (p[0] + p[1]) + (p[2] + p[3]);
        l_part += (racc[0] + racc[1]) + (racc[2] + racc[3]);

        unsigned pk[4][2];
        #pragma unroll
        for (int t = 0; t < 4; ++t) {
            pk[t][0] = BFPACK(p[t][0], p[t][1]);
            pk[t][1] = BFPACK(p[t][2], p[t][3]);
        }

        // ---- P^T strip (wave-private) ----
        *(unsigned long long*)pw0 = (unsigned long long)pk[0][0] | ((unsigned long long)pk[0][1] << 32);
        *(unsigned long long*)pw1 = (unsigned long long)pk[1][0] | ((unsigned long long)pk[1][1] << 32);
        *(unsigned long long*)pw2 = (unsigned long long)pk[2][0] | ((unsigned long long)pk[2][1] << 32);
        *(unsigned long long*)pw3 = (unsigned long long)pk[3][0] | ((unsigned long long)pk[3][1] << 32);

        // ---- O^T += V^T P^T ----
        __builtin_amdgcn_s_setprio(1);
        {
            bf16x8 pf0 = *(const bf16x8*)pr0;
            #pragma unroll
            for (int t = 0; t < 4; ++t) {
                bf16x8 vf = *(const bf16x8*)(kb0 + BOFF + 8192 + t * 2048);
                oacc[t] = __builtin_amdgcn_mfma_f32_16x16x32_bf16(vf, pf0, oacc[t], 0, 0, 0);
            }
            bf16x8 pf1 = *(const bf16x8*)pr1;
            #pragma unroll
            for (int t = 0; t < 4; ++t) {
                bf16x8 vf = *(const bf16x8*)(kb1 + BOFF + 8192 + t * 2048);
                oacc[t] = __builtin_amdgcn_mfma_f32_16x16x32_bf16(vf, pf1, oacc[t], 0, 0, 0);
            }
        }
        __builtin_amdgcn_s_setprio(0);
    };

    for (int i = 0; i < 16; ++i) {
        // body A: stage tile(2i+1) -> buf1, compute buf0
        GLL16(kgp, smem + 32768 + w * 1024);
        GLL16(vgp, smem + 40960 + w * 1024);
        kgp += 64 * HDIM;
        vgp += 64;
        tile(0);
        __syncthreads();
        // body B: stage tile(2i+2) -> buf0 (guarded), compute buf1
        if (i < 15) {
            GLL16(kgp, smem + 16384 + w * 1024);
            GLL16(vgp, smem + 24576 + w * 1024);
            kgp += 64 * HDIM;
            vgp += 64;
        }
        tile(16384);
        __syncthreads();
    }

    // ---- deferred l reduction + epilogue ----
    float l_r = l_part;
    l_r += __shfl_xor(l_r, 16);
    l_r += __shfl_xor(l_r, 32);
    float oinv = 1.f / l_r;
    {
        unsigned lo, hi;
        lo = BFPACK(oacc[0][0] * oinv, oacc[0][1] * oinv);
        hi = BFPACK(oacc[0][2] * oinv, oacc[0][3] * oinv);
        *(unsigned long long*)pw0 = (unsigned long long)lo | ((unsigned long long)hi << 32);
        lo = BFPACK(oacc[1][0] * oinv, oacc[1][1] * oinv);
        hi = BFPACK(oacc[1][2] * oinv, oacc[1][3] * oinv);
        *(unsigned long long*)pw1 = (unsigned long long)lo | ((unsigned long long)hi << 32);
        lo = BFPACK(oacc[2][0] * oinv, oacc[2][1] * oinv);
        hi = BFPACK(oacc[2][2] * oinv, oacc[2][3] * oinv);
        *(unsigned long long*)pw2 = (unsigned long long)lo | ((unsigned long long)hi << 32);
        lo = BFPACK(oacc[3][0] * oinv, oacc[3][1] * oinv);
        hi = BFPACK(oacc[3][2] * oinv, oacc[3][3] * oinv);
        *(unsigned long long*)pw3 = (unsigned long long)lo | ((unsigned long long)hi << 32);
    }
    char* wbase = smem + w * 2048;         // wave's 16 rows
    #pragma unroll
    for (int i = 0; i < 2; ++i) {
        int idx = L + i * 64;              // 128 chunks = 16 rows x 8x16B
        int row = idx >> 3, ch = idx & 7;
        bf16x8 v = *(const bf16x8*)(wbase + row * 128 + ((ch * 16) ^ ((row & 7) << 4)));
        *(bf16x8*)&at[((size_t)(b * N_DIM + q0 + w * 16 + row)) * C_DIM + hh * HDIM + ch * 8] = v;
    }
}

// ---------------------------------------------------------------------------
extern "C" void kernel_launch(void* const* d_in, const int* in_sizes, int n_in,
                              void* d_out, int out_size, void* d_ws, size_t ws_size,
                              hipStream_t stream) {
    (void)in_sizes; (void)n_in; (void)out_size; (void)ws_size;
    const float* x     = (const float*)d_in[0];
    const float* gam   = (const float*)d_in[1];
    const float* bet   = (const float*)d_in[2];
    const float* q_w   = (const float*)d_in[3];
    const float* q_b   = (const float*)d_in[4];
    const float* k_w   = (const float*)d_in[5];
    const float* k_b   = (const float*)d_in[6];
    const float* v_w   = (const float*)d_in[7];
    const float* v_b   = (const float*)d_in[8];
    const float* p_w   = (const float*)d_in[9];
    const float* p_b   = (const float*)d_in[10];
    float* out = (float*)d_out;

    const size_t MB = 1 << 20;
    char* wsb = (char*)d_ws;
    unsigned short* ht  = (unsigned short*)(wsb);              // 8 MB  [8192][512]
    unsigned short* wqb = (unsigned short*)(wsb + 8 * MB);     // 4 x 512KB contiguous (q,k,v,p)
    unsigned short* wpb = (unsigned short*)(wsb + 9 * MB + 512 * 1024);
    float*          partial = (float*)(wsb + 10 * MB);         // 2 KB
    unsigned short* qt  = (unsigned short*)(wsb + 11 * MB);    // 8 MB [bh][n][d]
    unsigned short* kt  = (unsigned short*)(wsb + 19 * MB);    // 8 MB
    unsigned short* vt  = (unsigned short*)(wsb + 27 * MB);    // 8 MB [b][c][n]
    unsigned short* at  = (unsigned short*)(wsb + 35 * MB);    // 8 MB [b][n][c]

    gn_stats<<<B_DIM * NGRP * 2, 256, 0, stream>>>(x, partial);
    gn_apply_t<<<dim3(N_DIM / 64, C_DIM / 64, B_DIM), 256, 0, stream>>>(x, partial, gam, bet, ht);

    cast4_bf16<<<dim3(128, 4), 256, 0, stream>>>(q_w, k_w, v_w, p_w, wqb);

    const float escale = 0.044194173824159216f * 1.4426950408889634f;  // scale*log2(e)
    conv_qkv<<<dim3(B_DIM * N_DIM / 128, C_DIM / 64), 512, 0, stream>>>(
        wqb, q_b, k_b, v_b, ht, qt, kt, vt, escale);

    attn_kernel<<<512, 512, 0, stream>>>(qt, kt, vt, at);

    conv_proj<<<dim3(B_DIM * N_DIM / 128, C_DIM / 64), 256, 0, stream>>>(wpb, p_b, at, x, out);
}

// Round 13
// 113.357 us; speedup vs baseline: 2.4761x; 1.0016x over previous
//
#include <hip/hip_runtime.h>
#include <hip/hip_bf16.h>
#include <math.h>

#define C_DIM 512
#define N_DIM 2048
#define B_DIM 4
#define NGRP 32
#define GCH 16          // channels per group
#define NHEAD 8
#define HDIM 64
#define EPSV 1e-6f

using f32x4  = __attribute__((ext_vector_type(4))) float;
using bf16x8 = __attribute__((ext_vector_type(8))) short;   // 8 bf16 raw bits (4 VGPRs)

// async global->LDS, 16B per lane; LDS dest = wave-uniform base + lane*16
#define GLL16(gp, lp) __builtin_amdgcn_global_load_lds( \
    (const __attribute__((address_space(1))) unsigned int*)(gp), \
    (__attribute__((address_space(3))) unsigned int*)(lp), 16, 0, 0)

// pack high-16 (truncated bf16) of two f32s: lo16 = a, hi16 = b
#define BFPACK(a, b) __builtin_amdgcn_perm(__float_as_uint(b), __float_as_uint(a), 0x07060302u)

static __device__ __forceinline__ unsigned short f2bf(float f) {
    union { __hip_bfloat16 h; unsigned short u; } cv;
    cv.h = __float2bfloat16(f);
    return cv.u;
}

// ---------------------------------------------------------------------------
// gn_stats: 2 blocks per (b,group) half-slab; partial sums.
// ---------------------------------------------------------------------------
__global__ __launch_bounds__(256) void gn_stats(const float* __restrict__ x,
                                                float* __restrict__ partial) {
    const int HSZ = GCH * N_DIM / 2;        // 16384 floats per half
    int blk = blockIdx.x;                   // 0..255
    const float4* x4 = (const float4*)(x + (size_t)blk * HSZ);
    int tid = threadIdx.x;

    float s = 0.f, ss = 0.f;
    #pragma unroll
    for (int it = 0; it < HSZ / 4 / 256; ++it) {
        float4 v = x4[tid + it * 256];
        s  += v.x + v.y + v.z + v.w;
        ss += v.x * v.x + v.y * v.y + v.z * v.z + v.w * v.w;
    }
    __shared__ float rs[256], rss[256];
    rs[tid] = s; rss[tid] = ss;
    __syncthreads();
    for (int off = 128; off > 0; off >>= 1) {
        if (tid < off) { rs[tid] += rs[tid + off]; rss[tid] += rss[tid + off]; }
        __syncthreads();
    }
    if (tid == 0) {
        partial[blk * 2]     = rs[0];
        partial[blk * 2 + 1] = rss[0];
    }
}

// ---------------------------------------------------------------------------
// gn_apply_t: x [b][c][n] fp32 -> ht [(b*n)][c] bf16 (normalized, transposed).
// ---------------------------------------------------------------------------
__global__ __launch_bounds__(256) void gn_apply_t(const float* __restrict__ x,
                                                  const float* __restrict__ partial,
                                                  const float* __restrict__ gamma,
                                                  const float* __restrict__ beta,
                                                  unsigned short* __restrict__ ht) {
    __shared__ char smem[8192];     // [64 n][64 c] bf16, rows 128B, XOR-swizzled
    const float GSZI = 1.f / (GCH * N_DIM);
    int n0 = blockIdx.x * 64, c0 = blockIdx.y * 64, b = blockIdx.z;
    int tid = threadIdx.x;
    #pragma unroll
    for (int it = 0; it < 4; ++it) {
        int idx = tid + it * 256;
        int ci = idx >> 4, n4 = (idx & 15) << 2;
        int cg = c0 + ci, grp = cg >> 4;
        int bg = b * NGRP + grp;
        float s  = partial[bg * 4]     + partial[bg * 4 + 2];
        float ss = partial[bg * 4 + 1] + partial[bg * 4 + 3];
        float mean = s * GSZI;
        float var  = ss * GSZI - mean * mean;
        float rstd = rsqrtf(var + EPSV);
        float ga = gamma[cg] * rstd, be = beta[cg] - mean * ga;
        float4 v = *(const float4*)&x[((size_t)b * C_DIM + cg) * N_DIM + n0 + n4];
        float vals[4] = {v.x, v.y, v.z, v.w};
        #pragma unroll
        for (int j = 0; j < 4; ++j) {
            int nl = n4 + j;
            *(unsigned short*)(smem + nl * 128 + ((ci * 2) ^ ((nl & 7) << 4))) =
                f2bf(vals[j] * ga + be);
        }
    }
    __syncthreads();
    #pragma unroll
    for (int i = 0; i < 2; ++i) {
        int idx = tid + i * 256;       // 512 chunks = 64 rows x 8x16B
        int row = idx >> 3, ch = idx & 7;
        bf16x8 v = *(const bf16x8*)(smem + row * 128 + ((ch * 16) ^ ((row & 7) << 4)));
        *(bf16x8*)&ht[((size_t)(b * N_DIM + n0 + row)) * C_DIM + c0 + ch * 8] = v;
    }
}

// ---------------------------------------------------------------------------
// cast4: fp32 -> bf16 for the four 512x512 weights in one launch.
// ---------------------------------------------------------------------------
__global__ __launch_bounds__(256) void cast4_bf16(const float* __restrict__ s0,
                                                  const float* __restrict__ s1,
                                                  const float* __restrict__ s2,
                                                  const float* __restrict__ s3,
                                                  unsigned short* __restrict__ dst) {
    int which = blockIdx.y;
    const float* src = (which == 0) ? s0 : (which == 1) ? s1 : (which == 2) ? s2 : s3;
    size_t idx = (size_t)blockIdx.x * 256 + threadIdx.x;
    const float4* s4 = (const float4*)src;
    float4 a = s4[idx * 2], b = s4[idx * 2 + 1];
    bf16x8 o;
    o[0] = (short)f2bf(a.x); o[1] = (short)f2bf(a.y);
    o[2] = (short)f2bf(a.z); o[3] = (short)f2bf(a.w);
    o[4] = (short)f2bf(b.x); o[5] = (short)f2bf(b.y);
    o[6] = (short)f2bf(b.z); o[7] = (short)f2bf(b.w);
    *(bf16x8*)&dst[(size_t)which * 262144 + idx * 8] = o;
}

// ---------------------------------------------------------------------------
// conv_qkv v2: fused Q/K/V convs. (Unchanged from R11.)
// ---------------------------------------------------------------------------
__global__ __launch_bounds__(512) void conv_qkv(const unsigned short* __restrict__ Wall,
                                                const float* __restrict__ q_b,
                                                const float* __restrict__ k_b,
                                                const float* __restrict__ v_b,
                                                const unsigned short* __restrict__ ht,
                                                unsigned short* __restrict__ qt,
                                                unsigned short* __restrict__ kt,
                                                unsigned short* __restrict__ vt,
                                                float escale) {
    __shared__ char smem[40960];     // Bs 16KB | As_q 8KB | As_k 8KB | As_v 8KB

    int bn0 = blockIdx.x * 128;      // flattened b*N + n
    int bo  = blockIdx.y * 64;
    int tid = threadIdx.x;
    int L = tid & 63, w = tid >> 6;
    int g = L >> 4, c = L & 15;
    int wr = w >> 2, wc = w & 3;

    f32x4 acc[3][2][2];
    #pragma unroll
    for (int w3 = 0; w3 < 3; ++w3)
        #pragma unroll
        for (int t = 0; t < 2; ++t)
            #pragma unroll
            for (int u = 0; u < 2; ++u) acc[w3][t][u] = f32x4{0.f, 0.f, 0.f, 0.f};

    for (int k0 = 0; k0 < C_DIM; k0 += 64) {
        if (w < 4) {
            #pragma unroll
            for (int i = 0; i < 4; ++i) {
                int j = w * 4 + i;
                int row = j * 8 + (L >> 3);
                int sl = (L & 7) ^ (row & 7);
                GLL16(ht + (size_t)(bn0 + row) * C_DIM + k0 + sl * 8, smem + j * 1024);
            }
        } else {
            #pragma unroll
            for (int i = 0; i < 6; ++i) {
                int j = (w - 4) * 6 + i;
                int w3 = j >> 3, jj = j & 7;
                int row = jj * 8 + (L >> 3);
                int sl = (L & 7) ^ (row & 7);
                GLL16(Wall + (size_t)w3 * 262144 + (size_t)(bo + row) * C_DIM + k0 + sl * 8,
                      smem + 16384 + j * 1024);
            }
        }
        __syncthreads();

        bf16x8 bfr[2][2];
        #pragma unroll
        for (int u = 0; u < 2; ++u) {
            int row = wc * 32 + u * 16 + c;
            #pragma unroll
            for (int ks = 0; ks < 2; ++ks)
                bfr[u][ks] = *(const bf16x8*)(smem + row * 128 +
                                              ((g * 16 + ks * 64) ^ ((row & 7) << 4)));
        }
        #pragma unroll
        for (int w3 = 0; w3 < 3; ++w3) {
            char* As = smem + 16384 + w3 * 8192;
            bf16x8 af[2][2];
            #pragma unroll
            for (int t = 0; t < 2; ++t) {
                int row = wr * 32 + t * 16 + c;
                #pragma unroll
                for (int ks = 0; ks < 2; ++ks)
                    af[t][ks] = *(const bf16x8*)(As + row * 128 +
                                                 ((g * 16 + ks * 64) ^ ((row & 7) << 4)));
            }
            #pragma unroll
            for (int ks = 0; ks < 2; ++ks)
                #pragma unroll
                for (int t = 0; t < 2; ++t)
                    #pragma unroll
                    for (int u = 0; u < 2; ++u)
                        acc[w3][t][u] = __builtin_amdgcn_mfma_f32_16x16x32_bf16(
                            af[t][ks], bfr[u][ks], acc[w3][t][u], 0, 0, 0);
        }
        __syncthreads();
    }

    int b  = bn0 >> 11;              // N_DIM = 2048
    int nb = bn0 & (N_DIM - 1);
    int hh = bo >> 6;
    int bh = b * NHEAD + hh;

    #pragma unroll
    for (int t = 0; t < 2; ++t)
        #pragma unroll
        for (int r = 0; r < 4; ++r) {
            int m = bo + wr * 32 + t * 16 + g * 4 + r;
            float bi = v_b[m];
            #pragma unroll
            for (int u = 0; u < 2; ++u) {
                int n = nb + wc * 32 + u * 16 + c;
                vt[((size_t)b * C_DIM + m) * N_DIM + n] = f2bf(acc[2][t][u][r] + bi);
            }
        }

    char* Ts = smem;                 // [128 n][64 d] swz
    #pragma unroll
    for (int pass = 0; pass < 2; ++pass) {
        const float* bias = pass ? k_b : q_b;
        float esc = pass ? 1.0f : escale;
        unsigned short* dst = pass ? kt : qt;
        __syncthreads();
        #pragma unroll
        for (int t = 0; t < 2; ++t)
            #pragma unroll
            for (int r = 0; r < 4; ++r) {
                int ml = wr * 32 + t * 16 + g * 4 + r;   // d
                float bi = bias[bo + ml];
                #pragma unroll
                for (int u = 0; u < 2; ++u) {
                    int nl = wc * 32 + u * 16 + c;       // 0..127
                    *(unsigned short*)(Ts + nl * 128 + ((ml * 2) ^ ((nl & 7) << 4))) =
                        f2bf((acc[pass][t][u][r] + bi) * esc);
                }
            }
        __syncthreads();
        #pragma unroll
        for (int i = 0; i < 2; ++i) {
            int idx = tid + i * 512;     // 1024 chunks = 128 rows x 8x16B
            int row = idx >> 3, ch = idx & 7;
            bf16x8 v = *(const bf16x8*)(Ts + row * 128 + ((ch * 16) ^ ((row & 7) << 4)));
            *(bf16x8*)&dst[((size_t)bh * N_DIM + nb + row) * HDIM + ch * 8] = v;
        }
    }
}

// ---------------------------------------------------------------------------
// conv_proj: out fp32 [b][c][n] + residual. (Unchanged.)
// ---------------------------------------------------------------------------
__global__ __launch_bounds__(256) void conv_proj(const unsigned short* __restrict__ Wb,
                                                 const float* __restrict__ bias,
                                                 const unsigned short* __restrict__ Bsrc,
                                                 const float* __restrict__ res,
                                                 float* __restrict__ outf) {
    __shared__ char smem[24576];
    int bn0 = blockIdx.x * 128;
    int bo  = blockIdx.y * 64;
    int tid = threadIdx.x;
    int L = tid & 63, w = tid >> 6;
    int g = L >> 4, c = L & 15;
    int wr = w >> 1, wc = w & 1;

    f32x4 acc[2][4];
    #pragma unroll
    for (int t = 0; t < 2; ++t)
        #pragma unroll
        for (int u = 0; u < 4; ++u) acc[t][u] = f32x4{0.f, 0.f, 0.f, 0.f};

    for (int k0 = 0; k0 < C_DIM; k0 += 64) {
        #pragma unroll
        for (int i = 0; i < 2; ++i) {
            int j = w * 2 + i;
            int ra = j * 8 + (L >> 3);
            int sl = (L & 7) ^ (ra & 7);
            GLL16(Wb + (size_t)(bo + ra) * C_DIM + k0 + sl * 8, smem + j * 1024);
        }
        #pragma unroll
        for (int i = 0; i < 4; ++i) {
            int j = w * 4 + i;
            int rb = j * 8 + (L >> 3);
            int sl = (L & 7) ^ (rb & 7);
            GLL16(Bsrc + (size_t)(bn0 + rb) * C_DIM + k0 + sl * 8, smem + 8192 + j * 1024);
        }
        __syncthreads();

        bf16x8 af[2][2], bfr[4][2];
        #pragma unroll
        for (int t = 0; t < 2; ++t) {
            int row = wr * 32 + t * 16 + c;
            #pragma unroll
            for (int ks = 0; ks < 2; ++ks)
                af[t][ks] = *(const bf16x8*)(smem + row * 128 +
                                             ((g * 16 + ks * 64) ^ ((row & 7) << 4)));
        }
        #pragma unroll
        for (int u = 0; u < 4; ++u) {
            int row = wc * 64 + u * 16 + c;
            #pragma unroll
            for (int ks = 0; ks < 2; ++ks)
                bfr[u][ks] = *(const bf16x8*)(smem + 8192 + row * 128 +
                                              ((g * 16 + ks * 64) ^ ((row & 7) << 4)));
        }
        #pragma unroll
        for (int ks = 0; ks < 2; ++ks)
            #pragma unroll
            for (int t = 0; t < 2; ++t)
                #pragma unroll
                for (int u = 0; u < 4; ++u)
                    acc[t][u] = __builtin_amdgcn_mfma_f32_16x16x32_bf16(
                        af[t][ks], bfr[u][ks], acc[t][u], 0, 0, 0);
        __syncthreads();
    }

    int b  = bn0 >> 11;
    int nb = bn0 & (N_DIM - 1);
    #pragma unroll
    for (int t = 0; t < 2; ++t)
        #pragma unroll
        for (int r = 0; r < 4; ++r) {
            int m = bo + wr * 32 + t * 16 + g * 4 + r;
            float bi = bias[m];
            #pragma unroll
            for (int u = 0; u < 4; ++u) {
                int n = nb + wc * 64 + u * 16 + c;
                size_t off = ((size_t)b * C_DIM + m) * N_DIM + n;
                outf[off] = acc[t][u][r] + bi + res[off];
            }
        }
}

// ---------------------------------------------------------------------------
// MFMA bf16 flash attention, swapped-operand form. 8 waves, QBLK=128.
// R13: T4 counted-vmcnt pipeline — raw s_barrier + s_waitcnt vmcnt(2);
// next-tile global_load_lds stays in flight across the barrier (never drain
// vmcnt to 0 in the main loop). XCD remap retained from R12.
// ---------------------------------------------------------------------------
__global__ __launch_bounds__(512, 4) void attn_kernel(const unsigned short* __restrict__ Qt,
                                                      const unsigned short* __restrict__ Kt,
                                                      const unsigned short* __restrict__ Vt,
                                                      unsigned short* __restrict__ at) {
    __shared__ char smem[49152];
    // [0,16K): Q staging -> P/O strips; [16K,32K): buf0 (K|V); [32K,48K): buf1

    // ---- XCD-aware remap (grid = 512 linear blocks, XCD = d % 8) ----
    int d = blockIdx.x;                // 0..511 dispatch id
    int xcd = d & 7;
    int slot = d >> 3;                 // 0..63 within XCD
    int bh = xcd + 8 * (slot >> 4);    // heads {xcd, xcd+8, xcd+16, xcd+24}
    int q0 = (slot & 15) * 128;

    int b = bh >> 3, hh = bh & 7;
    int tid = threadIdx.x;
    int L = tid & 63, w = tid >> 6;        // 8 waves
    int g = L >> 4, c = L & 15;

    const unsigned short* Qh = Qt + (size_t)bh * N_DIM * HDIM;
    const unsigned short* Kh = Kt + (size_t)bh * N_DIM * HDIM;
    const unsigned short* Vh = Vt + (size_t)bh * HDIM * N_DIM;

    // ---- prologue: stage Q (16 x 1KB) + K/V tile 0 into buf0, all async ----
    #pragma unroll
    for (int i = 0; i < 2; ++i) {
        int j = w * 2 + i;
        int row = j * 8 + (L >> 3);        // 0..127
        int sl = (L & 7) ^ (row & 7);
        GLL16(Qh + (size_t)(q0 + row) * HDIM + sl * 8, smem + j * 1024);
    }
    int srow = w * 8 + (L >> 3);           // staging row 0..63
    int ssl  = (L & 7) ^ (srow & 7);
    GLL16(Kh + (size_t)srow * HDIM + ssl * 8, smem + 16384 + w * 1024);
    GLL16(Vh + (size_t)srow * N_DIM + ssl * 8, smem + 24576 + w * 1024);
    __syncthreads();                       // full drain: Q + tile0 ready

    // ---- hoisted addresses ----
    int csw = (c & 7) << 4;
    char* kb0 = smem + 16384 + c * 128 + ((g * 16) ^ csw);        // K frag ks=0
    char* kb1 = smem + 16384 + c * 128 + ((g * 16 + 64) ^ csw);   // K frag ks=1
    char* pb  = smem + (w * 16 + c) * 128;                        // wave-private strip
    char* pw0 = pb + ((g * 8) ^ csw);
    char* pw1 = pb + ((32 + g * 8) ^ csw);
    char* pw2 = pb + ((64 + g * 8) ^ csw);
    char* pw3 = pb + ((96 + g * 8) ^ csw);
    char* pr0 = pb + ((g * 16) ^ csw);
    char* pr1 = pb + ((64 + g * 16) ^ csw);

    // Q fragments from strip region (same addresses as pr0/pr1)
    bf16x8 qf[2];
    qf[0] = *(const bf16x8*)pr0;
    qf[1] = *(const bf16x8*)pr1;

    // staging global pointers -> tile 1
    const unsigned short* kgp = Kh + (size_t)(64 + srow) * HDIM + ssl * 8;
    const unsigned short* vgp = Vh + (size_t)srow * N_DIM + 64 + ssl * 8;

    f32x4 oacc[4];
    #pragma unroll
    for (int t = 0; t < 4; ++t) oacc[t] = f32x4{0.f, 0.f, 0.f, 0.f};
    float m_r = -INFINITY, l_part = 0.f;

    auto tile = [&](int BOFF) {
        // ---- S^T = K Q^T : D[kpos=16t+4g+r][q=16w+c] ----
        f32x4 sacc[4];
        #pragma unroll
        for (int t = 0; t < 4; ++t) sacc[t] = f32x4{0.f, 0.f, 0.f, 0.f};
        __builtin_amdgcn_s_setprio(1);
        #pragma unroll
        for (int t = 0; t < 4; ++t) {
            bf16x8 kf0 = *(const bf16x8*)(kb0 + BOFF + t * 2048);
            bf16x8 kf1 = *(const bf16x8*)(kb1 + BOFF + t * 2048);
            sacc[t] = __builtin_amdgcn_mfma_f32_16x16x32_bf16(kf0, qf[0], sacc[t], 0, 0, 0);
            sacc[t] = __builtin_amdgcn_mfma_f32_16x16x32_bf16(kf1, qf[1], sacc[t], 0, 0, 0);
        }
        __builtin_amdgcn_s_setprio(0);

        // ---- softmax over kpos (exp2 domain); zero-shfl steady state ----
        float t0 = fmaxf(fmaxf(sacc[0][0], sacc[0][1]), sacc[0][2]);
        float t1 = fmaxf(fmaxf(sacc[0][3], sacc[1][0]), sacc[1][1]);
        float t2 = fmaxf(fmaxf(sacc[1][2], sacc[1][3]), sacc[2][0]);
        float t3 = fmaxf(fmaxf(sacc[2][1], sacc[2][2]), sacc[2][3]);
        float t4 = fmaxf(fmaxf(sacc[3][0], sacc[3][1]), sacc[3][2]);
        float mloc = fmaxf(fmaxf(fmaxf(t0, t1), fmaxf(t2, t3)), fmaxf(t4, sacc[3][3]));
        if (!__all(mloc - m_r <= 6.0f)) {       // rare: row max grew
            mloc = fmaxf(mloc, __shfl_xor(mloc, 16));
            mloc = fmaxf(mloc, __shfl_xor(mloc, 32));
            float mn = fmaxf(m_r, mloc);
            float fac = exp2f(m_r - mn);
            m_r = mn;
            l_part *= fac;
            #pragma unroll
            for (int t = 0; t < 4; ++t) oacc[t] = oacc[t] * fac;
        }
        f32x4 m4 = {m_r, m_r, m_r, m_r};
        f32x4 p[4];
        #pragma unroll
        for (int t = 0; t < 4; ++t) {
            f32x4 dd = sacc[t] - m4;
            p[t][0] = exp2f(dd[0]);
            p[t][1] = exp2f(dd[1]);
            p[t][2] = exp2f(dd[2]);
            p[t][3] = exp2f(dd[3]);
        }
        f32x4 racc = (p[0] + p[1]) + (p[2] + p[3]);
        l_part += (racc[0] + racc[1]) + (racc[2] + racc[3]);

        unsigned pk[4][2];
        #pragma unroll
        for (int t = 0; t < 4; ++t) {
            pk[t][0] = BFPACK(p[t][0], p[t][1]);
            pk[t][1] = BFPACK(p[t][2], p[t][3]);
        }

        // ---- P^T strip (wave-private) ----
        *(unsigned long long*)pw0 = (unsigned long long)pk[0][0] | ((unsigned long long)pk[0][1] << 32);
        *(unsigned long long*)pw1 = (unsigned long long)pk[1][0] | ((unsigned long long)pk[1][1] << 32);
        *(unsigned long long*)pw2 = (unsigned long long)pk[2][0] | ((unsigned long long)pk[2][1] << 32);
        *(unsigned long long*)pw3 = (unsigned long long)pk[3][0] | ((unsigned long long)pk[3][1] << 32);

        // ---- O^T += V^T P^T ----
        __builtin_amdgcn_s_setprio(1);
        {
            bf16x8 pf0 = *(const bf16x8*)pr0;
            #pragma unroll
            for (int t = 0; t < 4; ++t) {
                bf16x8 vf = *(const bf16x8*)(kb0 + BOFF + 8192 + t * 2048);
                oacc[t] = __builtin_amdgcn_mfma_f32_16x16x32_bf16(vf, pf0, oacc[t], 0, 0, 0);
            }
            bf16x8 pf1 = *(const bf16x8*)pr1;
            #pragma unroll
            for (int t = 0; t < 4; ++t) {
                bf16x8 vf = *(const bf16x8*)(kb1 + BOFF + 8192 + t * 2048);
                oacc[t] = __builtin_amdgcn_mfma_f32_16x16x32_bf16(vf, pf1, oacc[t], 0, 0, 0);
            }
        }
        __builtin_amdgcn_s_setprio(0);
    };

    // T4 pipeline helpers: raw barrier + compiler fence; counted vmcnt.
    #define ATTN_BARRIER() do { \
        __builtin_amdgcn_s_barrier(); \
        asm volatile("" ::: "memory"); \
    } while (0)
    #define ATTN_VMCNT2() do { \
        asm volatile("s_waitcnt vmcnt(2)" ::: "memory"); \
        __builtin_amdgcn_sched_barrier(0); \
    } while (0)
    #define ATTN_VMCNT0() do { \
        asm volatile("s_waitcnt vmcnt(0)" ::: "memory"); \
        __builtin_amdgcn_sched_barrier(0); \
    } while (0)

    // main loop: tiles 0..29 (paired), stage(i+1) in flight across barrier
    for (int i = 0; i < 15; ++i) {
        // tile 2i (buf0); stage tile 2i+1 -> buf1
        ATTN_BARRIER();
        GLL16(kgp, smem + 32768 + w * 1024);
        GLL16(vgp, smem + 40960 + w * 1024);
        kgp += 64 * HDIM;
        vgp += 64;
        ATTN_VMCNT2();
        tile(0);
        // tile 2i+1 (buf1); stage tile 2i+2 -> buf0
        ATTN_BARRIER();
        GLL16(kgp, smem + 16384 + w * 1024);
        GLL16(vgp, smem + 24576 + w * 1024);
        kgp += 64 * HDIM;
        vgp += 64;
        ATTN_VMCNT2();
        tile(16384);
    }
    // tile 30 (buf0); stage tile 31 -> buf1
    ATTN_BARRIER();
    GLL16(kgp, smem + 32768 + w * 1024);
    GLL16(vgp, smem + 40960 + w * 1024);
    ATTN_VMCNT2();
    tile(0);
    // tile 31 (buf1); no more staging -> full drain
    ATTN_BARRIER();
    ATTN_VMCNT0();
    tile(16384);

    #undef ATTN_BARRIER
    #undef ATTN_VMCNT2
    #undef ATTN_VMCNT0

    // ---- deferred l reduction + epilogue (wave-private strip) ----
    float l_r = l_part;
    l_r += __shfl_xor(l_r, 16);
    l_r += __shfl_xor(l_r, 32);
    float oinv = 1.f / l_r;
    {
        unsigned lo, hi;
        lo = BFPACK(oacc[0][0] * oinv, oacc[0][1] * oinv);
        hi = BFPACK(oacc[0][2] * oinv, oacc[0][3] * oinv);
        *(unsigned long long*)pw0 = (unsigned long long)lo | ((unsigned long long)hi << 32);
        lo = BFPACK(oacc[1][0] * oinv, oacc[1][1] * oinv);
        hi = BFPACK(oacc[1][2] * oinv, oacc[1][3] * oinv);
        *(unsigned long long*)pw1 = (unsigned long long)lo | ((unsigned long long)hi << 32);
        lo = BFPACK(oacc[2][0] * oinv, oacc[2][1] * oinv);
        hi = BFPACK(oacc[2][2] * oinv, oacc[2][3] * oinv);
        *(unsigned long long*)pw2 = (unsigned long long)lo | ((unsigned long long)hi << 32);
        lo = BFPACK(oacc[3][0] * oinv, oacc[3][1] * oinv);
        hi = BFPACK(oacc[3][2] * oinv, oacc[3][3] * oinv);
        *(unsigned long long*)pw3 = (unsigned long long)lo | ((unsigned long long)hi << 32);
    }
    char* wbase = smem + w * 2048;         // wave's 16 rows
    #pragma unroll
    for (int i = 0; i < 2; ++i) {
        int idx = L + i * 64;              // 128 chunks = 16 rows x 8x16B
        int row = idx >> 3, ch = idx & 7;
        bf16x8 v = *(const bf16x8*)(wbase + row * 128 + ((ch * 16) ^ ((row & 7) << 4)));
        *(bf16x8*)&at[((size_t)(b * N_DIM + q0 + w * 16 + row)) * C_DIM + hh * HDIM + ch * 8] = v;
    }
}

// ---------------------------------------------------------------------------
extern "C" void kernel_launch(void* const* d_in, const int* in_sizes, int n_in,
                              void* d_out, int out_size, void* d_ws, size_t ws_size,
                              hipStream_t stream) {
    (void)in_sizes; (void)n_in; (void)out_size; (void)ws_size;
    const float* x     = (const float*)d_in[0];
    const float* gam   = (const float*)d_in[1];
    const float* bet   = (const float*)d_in[2];
    const float* q_w   = (const float*)d_in[3];
    const float* q_b   = (const float*)d_in[4];
    const float* k_w   = (const float*)d_in[5];
    const float* k_b   = (const float*)d_in[6];
    const float* v_w   = (const float*)d_in[7];
    const float* v_b   = (const float*)d_in[8];
    const float* p_w   = (const float*)d_in[9];
    const float* p_b   = (const float*)d_in[10];
    float* out = (float*)d_out;

    const size_t MB = 1 << 20;
    char* wsb = (char*)d_ws;
    unsigned short* ht  = (unsigned short*)(wsb);              // 8 MB  [8192][512]
    unsigned short* wqb = (unsigned short*)(wsb + 8 * MB);     // 4 x 512KB contiguous (q,k,v,p)
    unsigned short* wpb = (unsigned short*)(wsb + 9 * MB + 512 * 1024);
    float*          partial = (float*)(wsb + 10 * MB);         // 2 KB
    unsigned short* qt  = (unsigned short*)(wsb + 11 * MB);    // 8 MB [bh][n][d]
    unsigned short* kt  = (unsigned short*)(wsb + 19 * MB);    // 8 MB
    unsigned short* vt  = (unsigned short*)(wsb + 27 * MB);    // 8 MB [b][c][n]
    unsigned short* at  = (unsigned short*)(wsb + 35 * MB);    // 8 MB [b][n][c]

    gn_stats<<<B_DIM * NGRP * 2, 256, 0, stream>>>(x, partial);
    gn_apply_t<<<dim3(N_DIM / 64, C_DIM / 64, B_DIM), 256, 0, stream>>>(x, partial, gam, bet, ht);

    cast4_bf16<<<dim3(128, 4), 256, 0, stream>>>(q_w, k_w, v_w, p_w, wqb);

    const float escale = 0.044194173824159216f * 1.4426950408889634f;  // scale*log2(e)
    conv_qkv<<<dim3(B_DIM * N_DIM / 128, C_DIM / 64), 512, 0, stream>>>(
        wqb, q_b, k_b, v_b, ht, qt, kt, vt, escale);

    attn_kernel<<<512, 512, 0, stream>>>(qt, kt, vt, at);

    conv_proj<<<dim3(B_DIM * N_DIM / 128, C_DIM / 64), 256, 0, stream>>>(wpb, p_b, at, x, out);
}